// Round 12
// baseline (487.848 us; speedup 1.0000x reference)
//
#include <hip/hip_runtime.h>

#define NN 50000
#define NE 600000
#define NG 512
#define HD 128
#define EPSV 1e-5f
#define NSC 64                    // stats scatter copies
#define PL ((NN + 1) * 16)        // plane stride in uints (64B rows, +pad row)

typedef unsigned int uint;

__device__ inline void atomicAddF(float* p, float v) {
  __hip_atomic_fetch_add(p, v, __ATOMIC_RELAXED, __HIP_MEMORY_SCOPE_AGENT);
}

__device__ inline uint bf16rne(float f) {
  uint u = __float_as_uint(f);
  return (u + 0x7fffu + ((u >> 16) & 1u)) >> 16;
}
__device__ inline uint pack2bf(float a, float b) {
  return bf16rne(a) | (bf16rne(b) << 16);
}
__device__ inline float lo16f(uint u) { return __uint_as_float(u << 16); }
__device__ inline float hi16f(uint u) { return __uint_as_float(u & 0xffff0000u); }

// ---- prologue 1: count (blocks 0..2343) + tabs (2344..2814) + bsearch (2815..2817)
__global__ __launch_bounds__(256) void k_pro1(const int* __restrict__ dst, int* __restrict__ cnt,
                                              const float* __restrict__ emb0, const float* __restrict__ emb1,
                                              const float* __restrict__ emb2, const float* __restrict__ emb5,
                                              const float* __restrict__ W1, float* __restrict__ tabs,
                                              float* __restrict__ row0, const int* __restrict__ batch,
                                              int* __restrict__ gstart) {
  const int bid = blockIdx.x, t = threadIdx.x;
  if (bid < 2344) {
    int e = bid * 256 + t;
    if (e < NE) atomicAdd(&cnt[dst[e]], 1);
    return;
  }
  if (bid < 2815) {
    if (t >= 128) return;
    int r = bid - 2344, f = t;
    if (r == 470) { row0[f] = W1[f]; return; }
    const float* e;
    int wbase;
    if (r < 96)      { e = emb0 + r * 32;         wbase = 1;  }
    else if (r < 192){ e = emb1 + (r - 96) * 32;  wbase = 33; }
    else if (r < 288){ e = emb2 + (r - 192) * 32; wbase = 65; }
    else             { e = emb5 + (r - 288) * 32; wbase = 97; }
    float acc = 0.f;
#pragma unroll 8
    for (int k = 0; k < 32; k++) acc += e[k] * W1[(wbase + k) * HD + f];
    tabs[r * HD + f] = acc;
    return;
  }
  {
    int g = (bid - 2815) * 256 + t;
    if (g > NG) return;
    if (g == NG) { gstart[NG] = NN; return; }
    int lo = 0, hi = NN;
    while (lo < hi) {
      int mid = (lo + hi) >> 1;
      if (batch[mid] < g) lo = mid + 1;
      else hi = mid;
    }
    gstart[g] = lo;
  }
}

// ---- 3-phase scan over deg+1 (tile = 4096 elems/block, 13 blocks) ----
__global__ __launch_bounds__(1024) void k_scanA(const int* __restrict__ cnt, int* __restrict__ partials) {
  int t = threadIdx.x;
  int i0 = blockIdx.x * 4096 + 4 * t;
  int s = 0;
#pragma unroll
  for (int j = 0; j < 4; j++) {
    int idx = i0 + j;
    s += (idx < NN) ? (cnt[idx] + 1) : 0;
  }
#pragma unroll
  for (int d = 1; d < 64; d <<= 1) s += __shfl_xor(s, d);
  __shared__ int wsum[16];
  if ((t & 63) == 0) wsum[t >> 6] = s;
  __syncthreads();
  if (t == 0) {
    int tot = 0;
#pragma unroll
    for (int i = 0; i < 16; i++) tot += wsum[i];
    partials[blockIdx.x] = tot;
  }
}

__global__ __launch_bounds__(64) void k_scanB(int* __restrict__ partials, int* __restrict__ off) {
  if (threadIdx.x == 0) {
    int acc = 0;
#pragma unroll
    for (int i = 0; i < 13; i++) { int v = partials[i]; partials[i] = acc; acc += v; }
    partials[13] = acc;
    off[NN] = acc;
  }
}

__global__ __launch_bounds__(1024) void k_scanC(const int* __restrict__ cnt, const int* __restrict__ partials,
                                                int* __restrict__ off, int* __restrict__ cursor,
                                                float* __restrict__ dinv, int* __restrict__ csr,
                                                uint* __restrict__ Abf) {
  __shared__ int part[16];
  __shared__ int partscan[16];
  int t = threadIdx.x;
  int lane = t & 63, w = t >> 6;
  if (blockIdx.x == 0 && t < 64) {
    // zero the pad row NN in each of the 4 planes (16 uints each)
    Abf[(size_t)(t >> 4) * PL + (size_t)NN * 16 + (t & 15)] = 0u;
  }
  int i0 = blockIdx.x * 4096 + 4 * t;
  int c[4], v[4];
#pragma unroll
  for (int j = 0; j < 4; j++) {
    int idx = i0 + j;
    c[j] = (idx < NN) ? cnt[idx] : 0;
    v[j] = (idx < NN) ? (c[j] + 1) : 0;
  }
  int tsum = (v[0] + v[1]) + (v[2] + v[3]);
  int val = tsum;
#pragma unroll
  for (int s = 1; s < 64; s <<= 1) {
    int u = __shfl_up(val, s);
    if (lane >= s) val += u;
  }
  if (lane == 63) part[w] = val;
  __syncthreads();
  if (t == 0) {
    int acc = 0;
#pragma unroll
    for (int i = 0; i < 16; i++) { acc += part[i]; partscan[i] = acc; }
  }
  __syncthreads();
  int waveoff = (w > 0) ? partscan[w - 1] : 0;
  int run = val - tsum + waveoff + partials[blockIdx.x];
#pragma unroll
  for (int j = 0; j < 4; j++) {
    int idx = i0 + j;
    if (idx < NN) {
      off[idx] = run;
      cursor[idx] = run + 1;
      csr[run] = idx;                        // self-edge
      dinv[idx] = rsqrtf((float)c[j] + 1.0f);
      run += v[j];
    }
  }
}

// ---- prologue 2: fill (blocks 0..2343) + embed (2344..14843, plane writes) ----
__global__ __launch_bounds__(256) void k_pro2(const int* __restrict__ src, const int* __restrict__ dst,
                                              int* __restrict__ cursor, int* __restrict__ csr,
                                              const float* __restrict__ x, const float2* __restrict__ tabs2,
                                              const float2* __restrict__ row02, const float* __restrict__ dinv,
                                              uint* __restrict__ Abf) {
  const int bid = blockIdx.x, t = threadIdx.x;
  if (bid < 2344) {
    int e = bid * 256 + t;
    if (e < NE) {
      int p = atomicAdd(&cursor[dst[e]], 1);
      csr[p] = src[e];
    }
    return;
  }
  int n = (bid - 2344) * 4 + (t >> 6);   // exact: 12500*4 = NN
  int lane = t & 63;
  float poss = x[n * 5 + 0];
  int i0 = (int)x[n * 5 + 1];
  int i1 = (int)x[n * 5 + 2];
  int i2 = (int)x[n * 5 + 3];
  int i5 = (int)x[n * 5 + 4];
  float2 r0 = row02[lane];
  float2 t0 = tabs2[(size_t)i0 * 64 + lane];
  float2 t1 = tabs2[(size_t)(96 + i1) * 64 + lane];
  float2 t2 = tabs2[(size_t)(192 + i2) * 64 + lane];
  float2 t5 = tabs2[(size_t)(288 + i5) * 64 + lane];
  float hx = poss * r0.x + t0.x + t1.x + t2.x + t5.x;
  float hy = poss * r0.y + t0.y + t1.y + t2.y + t5.y;
  float dv = dinv[n];
  // features (2*lane, 2*lane+1) -> plane lane>>4, row n, uint lane&15
  Abf[(size_t)(lane >> 4) * PL + (size_t)n * 16 + (lane & 15)] = pack2bf(hx * dv, hy * dv);
}

// ---- aggregation v12: v11 planes + FIXED stats (single replica, lanes 0-15).
// After the full butterfly o[] is uniform per c4, so lanes 0-15 alone cover
// all (qduty,c4) combos exactly once -- v11's xor-16/32 reduce counted 4x.
#define AGG_NPW 4
#define AGG_NPB (4 * AGG_NPW)
__global__ __launch_bounds__(256) void k_agg(const uint* __restrict__ Abf, const int* __restrict__ off,
                                             const int* __restrict__ csr, const float* __restrict__ dinv,
                                             const float* __restrict__ bias, float* __restrict__ B,
                                             float* __restrict__ stats) {
  const int t = threadIdx.x, lane = t & 63, wave = t >> 6;
  const int g16 = lane >> 2, c4 = lane & 3;
  const int qduty = g16 & 3;
  __shared__ float sred[256];
  sred[t] = 0.f;
  __syncthreads();

  const int n0 = blockIdx.x * AGG_NPB + wave * AGG_NPW;   // grid exact
  int sv = 0; float dvv = 0.f;
  {
    int q = n0 + lane;
    if (lane <= AGG_NPW) sv = off[q];
    if (lane < AGG_NPW) dvv = dinv[q];
  }

  // preload all 4 nodes' first-64 edge indices
  int ev[AGG_NPW];
#pragma unroll
  for (int i = 0; i < AGG_NPW; i++) {
    int ks = __shfl(sv, i), ke = __shfl(sv, i + 1);
    int rem = ke - ks;
    ev[i] = (lane < rem) ? csr[ks + lane] : NN;
  }

  float st1[8] = {0.f, 0.f, 0.f, 0.f, 0.f, 0.f, 0.f, 0.f};
  float st2[8] = {0.f, 0.f, 0.f, 0.f, 0.f, 0.f, 0.f, 0.f};

#pragma unroll
  for (int q = 0; q < 4; q++) {
    __syncthreads();   // phase fence: drain loads, keep the grid on one plane
    const char* Pq = (const char*)(Abf + (size_t)q * PL);
    // lead gathers: 1 instr/node covers 16 neighbor rows (pads -> row NN)
    int nb0 = __shfl(ev[0], g16);
    int nb1 = __shfl(ev[1], g16);
    int nb2 = __shfl(ev[2], g16);
    int nb3 = __shfl(ev[3], g16);
    uint4 v0 = *(const uint4*)(Pq + ((size_t)nb0 << 6) + (c4 << 4));
    uint4 v1 = *(const uint4*)(Pq + ((size_t)nb1 << 6) + (c4 << 4));
    uint4 v2 = *(const uint4*)(Pq + ((size_t)nb2 << 6) + (c4 << 4));
    uint4 v3 = *(const uint4*)(Pq + ((size_t)nb3 << 6) + (c4 << 4));
    const float4 ba = ((const float4*)bias)[q * 8 + c4 * 2];
    const float4 bb = ((const float4*)bias)[q * 8 + c4 * 2 + 1];
#pragma unroll
    for (int i = 0; i < AGG_NPW; i++) {
      uint4 vv = (i == 0) ? v0 : (i == 1) ? v1 : (i == 2) ? v2 : v3;
      float acc[8];
      acc[0] = lo16f(vv.x); acc[1] = hi16f(vv.x);
      acc[2] = lo16f(vv.y); acc[3] = hi16f(vv.y);
      acc[4] = lo16f(vv.z); acc[5] = hi16f(vv.z);
      acc[6] = lo16f(vv.w); acc[7] = hi16f(vv.w);
      const int ks = __shfl(sv, i), ke = __shfl(sv, i + 1);
      const int deg = ke - ks;
      // tail: edges 16..deg (P(deg>16) ~ 16%)
#pragma unroll 1
      for (int c0 = 16; c0 < deg; c0 += 16) {
        int nb;
        if (c0 < 64) {
          nb = __shfl(ev[i], c0 + g16);        // pads give NN
        } else {
          int rem2 = deg - c0;
          int evr = (lane < rem2) ? csr[ks + c0 + lane] : NN;
          nb = __shfl(evr, g16);
        }
        uint4 w = *(const uint4*)(Pq + ((size_t)nb << 6) + (c4 << 4));
        acc[0] += lo16f(w.x); acc[1] += hi16f(w.x);
        acc[2] += lo16f(w.y); acc[3] += hi16f(w.y);
        acc[4] += lo16f(w.z); acc[5] += hi16f(w.z);
        acc[6] += lo16f(w.w); acc[7] += hi16f(w.w);
      }
      // combine 16 groups (disjoint neighbor subsets) -> o uniform per c4
#pragma unroll
      for (int j = 0; j < 8; j++) {
        acc[j] += __shfl_xor(acc[j], 4);
        acc[j] += __shfl_xor(acc[j], 8);
        acc[j] += __shfl_xor(acc[j], 16);
        acc[j] += __shfl_xor(acc[j], 32);
      }
      const float dv = __shfl(dvv, i);
      float o[8];
      o[0] = fmaf(acc[0], dv, ba.x); o[1] = fmaf(acc[1], dv, ba.y);
      o[2] = fmaf(acc[2], dv, ba.z); o[3] = fmaf(acc[3], dv, ba.w);
      o[4] = fmaf(acc[4], dv, bb.x); o[5] = fmaf(acc[5], dv, bb.y);
      o[6] = fmaf(acc[6], dv, bb.z); o[7] = fmaf(acc[7], dv, bb.w);
      if (g16 == 0) {
        *(float4*)&B[(size_t)(n0 + i) * HD + q * 32 + c4 * 8]     = make_float4(o[0], o[1], o[2], o[3]);
        *(float4*)&B[(size_t)(n0 + i) * HD + q * 32 + c4 * 8 + 4] = make_float4(o[4], o[5], o[6], o[7]);
      }
      // FIXED: single-replica stats -- only lanes 0-15 accumulate
      if (qduty == q && lane < 16) {
#pragma unroll
        for (int j = 0; j < 8; j++) { st1[j] += o[j]; st2[j] += o[j] * o[j]; }
      }
    }
  }
  if (lane < 16) {
    int fb = qduty * 32 + c4 * 8;
#pragma unroll
    for (int j = 0; j < 8; j++) {
      atomicAdd(&sred[fb + j], st1[j]);
      atomicAdd(&sred[128 + fb + j], st2[j]);
    }
  }
  __syncthreads();
  float* sp = stats + ((blockIdx.x & (NSC - 1)) << 8);   // 64-way scatter
  atomicAddF(&sp[t], sred[t]);
}

// ---- GEMM (BN affine computed in-block from stats): Abf planes out ----
#define GT_N 128
#define GT_KC 32
__global__ __launch_bounds__(256) void k_gemm(const float* __restrict__ Bin, const float* __restrict__ W,
                                              const float* __restrict__ stats, const float* __restrict__ gg,
                                              const float* __restrict__ be, const float* __restrict__ dinv,
                                              uint* __restrict__ Abf) {
  __shared__ float hs[GT_KC * 132];
  __shared__ float ws[GT_KC * 132];
  __shared__ float afl[128], cfl[128];
  const int t = threadIdx.x;
  if (t < 128) {
    float s1 = 0.f, s2 = 0.f;
#pragma unroll 4
    for (int i = 0; i < NSC; i++) {
      s1 += stats[i * 256 + t];
      s2 += stats[i * 256 + 128 + t];
    }
    float mean = s1 * (1.f / NN);
    float var = fmaxf(s2 * (1.f / NN) - mean * mean, 0.f);
    float inv = rsqrtf(var + EPSV);
    float a = gg[t] * inv;
    afl[t] = a;
    cfl[t] = be[t] - mean * a;
  }
  __syncthreads();

  const int base = blockIdx.x * GT_N;
  const int tx = t & 15, ty = t >> 4;
  float acc[8][8];
#pragma unroll
  for (int a = 0; a < 8; a++)
#pragma unroll
    for (int b = 0; b < 8; b++) acc[a][b] = 0.f;

  for (int k0 = 0; k0 < HD; k0 += GT_KC) {
    __syncthreads();
    {
      const float4* W4 = (const float4*)(W + k0 * HD);
#pragma unroll
      for (int i = t; i < 1024; i += 256) {
        int row = i >> 5, c4i = i & 31;
        float4 v = W4[i];
        *(float4*)&ws[row * 132 + c4i * 4] = v;
      }
    }
    {
#pragma unroll
      for (int i = t; i < 1024; i += 256) {
        int node = i >> 3, c4i = i & 7;
        int n = base + node;
        float4 v = make_float4(0.f, 0.f, 0.f, 0.f);
        if (n < NN) v = *(const float4*)&Bin[(size_t)n * HD + k0 + c4i * 4];
        int kk = c4i * 4;
        float r0 = fmaxf(fmaf(afl[k0 + kk + 0], v.x, cfl[k0 + kk + 0]), 0.f);
        float r1 = fmaxf(fmaf(afl[k0 + kk + 1], v.y, cfl[k0 + kk + 1]), 0.f);
        float r2 = fmaxf(fmaf(afl[k0 + kk + 2], v.z, cfl[k0 + kk + 2]), 0.f);
        float r3 = fmaxf(fmaf(afl[k0 + kk + 3], v.w, cfl[k0 + kk + 3]), 0.f);
        hs[(kk + 0) * 132 + node] = r0;
        hs[(kk + 1) * 132 + node] = r1;
        hs[(kk + 2) * 132 + node] = r2;
        hs[(kk + 3) * 132 + node] = r3;
      }
    }
    __syncthreads();
#pragma unroll
    for (int k = 0; k < GT_KC; k++) {
      float4 h0 = *(float4*)&hs[k * 132 + ty * 8];
      float4 h1 = *(float4*)&hs[k * 132 + ty * 8 + 4];
      float4 w0 = *(float4*)&ws[k * 132 + tx * 8];
      float4 w1 = *(float4*)&ws[k * 132 + tx * 8 + 4];
      float hh[8] = {h0.x, h0.y, h0.z, h0.w, h1.x, h1.y, h1.z, h1.w};
      float wv[8] = {w0.x, w0.y, w0.z, w0.w, w1.x, w1.y, w1.z, w1.w};
#pragma unroll
      for (int a = 0; a < 8; a++)
#pragma unroll
        for (int b = 0; b < 8; b++) acc[a][b] = fmaf(hh[a], wv[b], acc[a][b]);
    }
  }
#pragma unroll
  for (int a = 0; a < 8; a++) {
    int n = base + ty * 8 + a;
    if (n < NN) {
      float s = dinv[n];
      uint4 o;
      o.x = pack2bf(acc[a][0] * s, acc[a][1] * s);
      o.y = pack2bf(acc[a][2] * s, acc[a][3] * s);
      o.z = pack2bf(acc[a][4] * s, acc[a][5] * s);
      o.w = pack2bf(acc[a][6] * s, acc[a][7] * s);
      // features tx*8..tx*8+7 -> plane tx>>2, row n, uints (tx&3)*4..
      *(uint4*)&Abf[(size_t)(tx >> 2) * PL + (size_t)n * 16 + (tx & 3) * 4] = o;
    }
  }
}

// ---- pool + FC (affine folded in; 2 node-lanes x 128 features) ----
__global__ __launch_bounds__(256) void k_pool(const float* __restrict__ B, const float* __restrict__ stats,
                                              const float* __restrict__ gg, const float* __restrict__ be,
                                              const int* __restrict__ gstart,
                                              const float* __restrict__ fcW, const float* __restrict__ fcb,
                                              float* __restrict__ out) {
  __shared__ float afl[128], cfl[128];
  int t = threadIdx.x;
  if (t < 128) {
    float s1 = 0.f, s2 = 0.f;
#pragma unroll 4
    for (int i = 0; i < NSC; i++) {
      s1 += stats[i * 256 + t];
      s2 += stats[i * 256 + 128 + t];
    }
    float mean = s1 * (1.f / NN);
    float var = fmaxf(s2 * (1.f / NN) - mean * mean, 0.f);
    float inv = rsqrtf(var + EPSV);
    float a = gg[t] * inv;
    afl[t] = a;
    cfl[t] = be[t] - mean * a;
  }
  __syncthreads();

  int g = blockIdx.x;
  int r = t >> 7, f = t & 127;
  int gs = gstart[g], ge = gstart[g + 1];
  float a = afl[f], c = cfl[f];
  float a0 = 0.f, a1 = 0.f, a2 = 0.f, a3 = 0.f;
  int n = gs + r;
  for (; n + 6 < ge; n += 8) {
    a0 += fmaxf(fmaf(a, B[(size_t)(n + 0) * HD + f], c), 0.f);
    a1 += fmaxf(fmaf(a, B[(size_t)(n + 2) * HD + f], c), 0.f);
    a2 += fmaxf(fmaf(a, B[(size_t)(n + 4) * HD + f], c), 0.f);
    a3 += fmaxf(fmaf(a, B[(size_t)(n + 6) * HD + f], c), 0.f);
  }
  for (; n < ge; n += 2) a0 += fmaxf(fmaf(a, B[(size_t)n * HD + f], c), 0.f);
  float acc = (a0 + a1) + (a2 + a3);
  __shared__ float lp[256];
  lp[t] = acc;
  __syncthreads();
  if (r == 0) {
    float pooled = (lp[f] + lp[f + 128]) / fmaxf((float)(ge - gs), 1.f);
    lp[f] = pooled;
  }
  __syncthreads();
  if (t < 3) {
    float o = fcb[t];
    for (int k = 0; k < 128; k++) o += lp[k] * fcW[k * 3 + t];
    out[g * 3 + t] = o;
  }
}

extern "C" void kernel_launch(void* const* d_in, const int* in_sizes, int n_in,
                              void* d_out, int out_size, void* d_ws, size_t ws_size,
                              hipStream_t stream) {
  const float* x    = (const float*)d_in[0];
  const int* ei     = (const int*)d_in[1];
  const int* batch  = (const int*)d_in[2];
  const float* emb0 = (const float*)d_in[3];
  const float* emb1 = (const float*)d_in[4];
  const float* emb2 = (const float*)d_in[5];
  const float* emb5 = (const float*)d_in[6];
  const float* W1   = (const float*)d_in[7];
  const float* b1   = (const float*)d_in[8];
  const float* W2   = (const float*)d_in[9];
  const float* b2   = (const float*)d_in[10];
  const float* W3   = (const float*)d_in[11];
  const float* b3   = (const float*)d_in[12];
  const float* g1   = (const float*)d_in[13];
  const float* be1  = (const float*)d_in[14];
  const float* g2   = (const float*)d_in[15];
  const float* be2  = (const float*)d_in[16];
  const float* g3   = (const float*)d_in[17];
  const float* be3  = (const float*)d_in[18];
  const float* fcW  = (const float*)d_in[19];
  const float* fcb  = (const float*)d_in[20];
  float* out = (float*)d_out;

  const int* esrc = ei;
  const int* edst = ei + NE;

  char* p = (char*)d_ws;
  size_t o = 0;
  auto alloc = [&](size_t bytes) -> void* {
    o = (o + 255) & ~(size_t)255;
    void* r = p + o;
    o += bytes;
    return r;
  };
  int* cnt      = (int*)alloc(NN * 4);
  float* stats  = (float*)alloc(3 * NSC * 256 * 4);   // 3 layers x 64 copies x (sum,sumsq)
  size_t zbytes = o;                                  // memset covers cnt+stats
  int* off      = (int*)alloc((NN + 1) * 4);
  int* cursor   = (int*)alloc(NN * 4);
  int* csr      = (int*)alloc((size_t)(NE + NN + 64) * 4);
  float* dinv   = (float*)alloc(NN * 4);
  float* tabs   = (float*)alloc(470 * HD * 4);
  float* row0   = (float*)alloc(HD * 4);
  int* gstart   = (int*)alloc((NG + 1) * 4);
  int* partials = (int*)alloc(16 * 4);
  uint* Abf     = (uint*)alloc((size_t)4 * PL * 4);   // 4 planes of 64B rows (+pad row each)
  float* bufB   = (float*)alloc((size_t)NN * HD * 4);
  (void)ws_size; (void)n_in; (void)in_sizes; (void)out_size;

  hipMemsetAsync(d_ws, 0, zbytes, stream);

  k_pro1<<<2818, 256, 0, stream>>>(edst, cnt, emb0, emb1, emb2, emb5, W1, tabs, row0, batch, gstart);
  k_scanA<<<13, 1024, 0, stream>>>(cnt, partials);
  k_scanB<<<1, 64, 0, stream>>>(partials, off);
  k_scanC<<<13, 1024, 0, stream>>>(cnt, partials, off, cursor, dinv, csr, Abf);
  k_pro2<<<14844, 256, 0, stream>>>(esrc, edst, cursor, csr, x, (const float2*)tabs,
                                    (const float2*)row0, dinv, Abf);

  const int nagg = NN / AGG_NPB;            // 3125, exact
  const int ngemm = (NN + GT_N - 1) / GT_N;
  float* st1 = stats;
  float* st2 = stats + NSC * 256;
  float* st3 = stats + 2 * NSC * 256;

  // layer 1
  k_agg<<<nagg, 256, 0, stream>>>(Abf, off, csr, dinv, b1, bufB, st1);
  // layer 2
  k_gemm<<<ngemm, 256, 0, stream>>>(bufB, W2, st1, g1, be1, dinv, Abf);
  k_agg<<<nagg, 256, 0, stream>>>(Abf, off, csr, dinv, b2, bufB, st2);
  // layer 3
  k_gemm<<<ngemm, 256, 0, stream>>>(bufB, W3, st2, g2, be2, dinv, Abf);
  k_agg<<<nagg, 256, 0, stream>>>(Abf, off, csr, dinv, b3, bufB, st3);
  // pool + fc
  k_pool<<<NG, 256, 0, stream>>>(bufB, st3, g3, be3, gstart, fcW, fcb, out);
}

// Round 13
// 445.557 us; speedup vs baseline: 1.0949x; 1.0949x over previous
//
#include <hip/hip_runtime.h>

#define NN 50000
#define NE 600000
#define NG 512
#define HD 128
#define EPSV 1e-5f
#define NSC 64                    // stats scatter copies

typedef unsigned int uint;

__device__ inline void atomicAddF(float* p, float v) {
  __hip_atomic_fetch_add(p, v, __ATOMIC_RELAXED, __HIP_MEMORY_SCOPE_AGENT);
}

__device__ inline uint bf16rne(float f) {
  uint u = __float_as_uint(f);
  return (u + 0x7fffu + ((u >> 16) & 1u)) >> 16;
}
__device__ inline uint pack2bf(float a, float b) {
  return bf16rne(a) | (bf16rne(b) << 16);
}
__device__ inline float lo16f(uint u) { return __uint_as_float(u << 16); }
__device__ inline float hi16f(uint u) { return __uint_as_float(u & 0xffff0000u); }

// ---- prologue 1: count (blocks 0..2343) + tabs (2344..2814) + bsearch (2815..2817)
__global__ __launch_bounds__(256) void k_pro1(const int* __restrict__ dst, int* __restrict__ cnt,
                                              const float* __restrict__ emb0, const float* __restrict__ emb1,
                                              const float* __restrict__ emb2, const float* __restrict__ emb5,
                                              const float* __restrict__ W1, float* __restrict__ tabs,
                                              float* __restrict__ row0, const int* __restrict__ batch,
                                              int* __restrict__ gstart) {
  const int bid = blockIdx.x, t = threadIdx.x;
  if (bid < 2344) {
    int e = bid * 256 + t;
    if (e < NE) atomicAdd(&cnt[dst[e]], 1);
    return;
  }
  if (bid < 2815) {
    if (t >= 128) return;
    int r = bid - 2344, f = t;
    if (r == 470) { row0[f] = W1[f]; return; }
    const float* e;
    int wbase;
    if (r < 96)      { e = emb0 + r * 32;         wbase = 1;  }
    else if (r < 192){ e = emb1 + (r - 96) * 32;  wbase = 33; }
    else if (r < 288){ e = emb2 + (r - 192) * 32; wbase = 65; }
    else             { e = emb5 + (r - 288) * 32; wbase = 97; }
    float acc = 0.f;
#pragma unroll 8
    for (int k = 0; k < 32; k++) acc += e[k] * W1[(wbase + k) * HD + f];
    tabs[r * HD + f] = acc;
    return;
  }
  {
    int g = (bid - 2815) * 256 + t;
    if (g > NG) return;
    if (g == NG) { gstart[NG] = NN; return; }
    int lo = 0, hi = NN;
    while (lo < hi) {
      int mid = (lo + hi) >> 1;
      if (batch[mid] < g) lo = mid + 1;
      else hi = mid;
    }
    gstart[g] = lo;
  }
}

// ---- 3-phase scan over deg+1 (tile = 4096 elems/block, 13 blocks) ----
__global__ __launch_bounds__(1024) void k_scanA(const int* __restrict__ cnt, int* __restrict__ partials) {
  int t = threadIdx.x;
  int i0 = blockIdx.x * 4096 + 4 * t;
  int s = 0;
#pragma unroll
  for (int j = 0; j < 4; j++) {
    int idx = i0 + j;
    s += (idx < NN) ? (cnt[idx] + 1) : 0;
  }
#pragma unroll
  for (int d = 1; d < 64; d <<= 1) s += __shfl_xor(s, d);
  __shared__ int wsum[16];
  if ((t & 63) == 0) wsum[t >> 6] = s;
  __syncthreads();
  if (t == 0) {
    int tot = 0;
#pragma unroll
    for (int i = 0; i < 16; i++) tot += wsum[i];
    partials[blockIdx.x] = tot;
  }
}

__global__ __launch_bounds__(64) void k_scanB(int* __restrict__ partials, int* __restrict__ off) {
  if (threadIdx.x == 0) {
    int acc = 0;
#pragma unroll
    for (int i = 0; i < 13; i++) { int v = partials[i]; partials[i] = acc; acc += v; }
    partials[13] = acc;
    off[NN] = acc;
  }
}

__global__ __launch_bounds__(1024) void k_scanC(const int* __restrict__ cnt, const int* __restrict__ partials,
                                                int* __restrict__ off, int* __restrict__ cursor,
                                                float* __restrict__ dinv, int* __restrict__ csr,
                                                uint* __restrict__ Abf) {
  __shared__ int part[16];
  __shared__ int partscan[16];
  int t = threadIdx.x;
  int lane = t & 63, w = t >> 6;
  if (blockIdx.x == 0 && t < 64) {
    Abf[(size_t)NN * 64 + t] = 0u;   // zero pad row (256B bf16 row = 64 uints)
  }
  int i0 = blockIdx.x * 4096 + 4 * t;
  int c[4], v[4];
#pragma unroll
  for (int j = 0; j < 4; j++) {
    int idx = i0 + j;
    c[j] = (idx < NN) ? cnt[idx] : 0;
    v[j] = (idx < NN) ? (c[j] + 1) : 0;
  }
  int tsum = (v[0] + v[1]) + (v[2] + v[3]);
  int val = tsum;
#pragma unroll
  for (int s = 1; s < 64; s <<= 1) {
    int u = __shfl_up(val, s);
    if (lane >= s) val += u;
  }
  if (lane == 63) part[w] = val;
  __syncthreads();
  if (t == 0) {
    int acc = 0;
#pragma unroll
    for (int i = 0; i < 16; i++) { acc += part[i]; partscan[i] = acc; }
  }
  __syncthreads();
  int waveoff = (w > 0) ? partscan[w - 1] : 0;
  int run = val - tsum + waveoff + partials[blockIdx.x];
#pragma unroll
  for (int j = 0; j < 4; j++) {
    int idx = i0 + j;
    if (idx < NN) {
      off[idx] = run;
      cursor[idx] = run + 1;
      csr[run] = idx;                        // self-edge
      dinv[idx] = rsqrtf((float)c[j] + 1.0f);
      run += v[j];
    }
  }
}

// ---- prologue 2: fill (blocks 0..2343) + embed (2344..14843) ----
__global__ __launch_bounds__(256) void k_pro2(const int* __restrict__ src, const int* __restrict__ dst,
                                              int* __restrict__ cursor, int* __restrict__ csr,
                                              const float* __restrict__ x, const float2* __restrict__ tabs2,
                                              const float2* __restrict__ row02, const float* __restrict__ dinv,
                                              uint* __restrict__ Abf) {
  const int bid = blockIdx.x, t = threadIdx.x;
  if (bid < 2344) {
    int e = bid * 256 + t;
    if (e < NE) {
      int p = atomicAdd(&cursor[dst[e]], 1);
      csr[p] = src[e];
    }
    return;
  }
  int n = (bid - 2344) * 4 + (t >> 6);   // exact: 12500*4 = NN
  int lane = t & 63;
  float poss = x[n * 5 + 0];
  int i0 = (int)x[n * 5 + 1];
  int i1 = (int)x[n * 5 + 2];
  int i2 = (int)x[n * 5 + 3];
  int i5 = (int)x[n * 5 + 4];
  float2 r0 = row02[lane];
  float2 t0 = tabs2[(size_t)i0 * 64 + lane];
  float2 t1 = tabs2[(size_t)(96 + i1) * 64 + lane];
  float2 t2 = tabs2[(size_t)(192 + i2) * 64 + lane];
  float2 t5 = tabs2[(size_t)(288 + i5) * 64 + lane];
  float hx = poss * r0.x + t0.x + t1.x + t2.x + t5.x;
  float hy = poss * r0.y + t0.y + t1.y + t2.y + t5.y;
  float dv = dinv[n];
  Abf[(size_t)n * 64 + lane] = pack2bf(hx * dv, hy * dv);
}

// ---- aggregation (r10 winner): 256B bf16 rows, 4 rows per gather instr,
// all 4 nodes' first-batch (16 loads) issued upfront, fully-unrolled consume.
#define AGG_NPW 4
#define AGG_NPB (4 * AGG_NPW)
__global__ __launch_bounds__(256) void k_agg(const uint* __restrict__ Abf, const int* __restrict__ off,
                                             const int* __restrict__ csr, const float* __restrict__ dinv,
                                             const float* __restrict__ bias, float* __restrict__ B,
                                             float* __restrict__ stats) {
  const int t = threadIdx.x, lane = t & 63, wave = t >> 6;
  const int grp = lane >> 4, p = lane & 15;
  __shared__ float sredb[16][17];   // [p][8 sums + 8 sumsqs], padded
  for (int q = t; q < 16 * 17; q += 256) ((float*)sredb)[q] = 0.f;
  __syncthreads();

  const float4 bias03 = ((const float4*)bias)[p * 2];
  const float4 bias47 = ((const float4*)bias)[p * 2 + 1];

  const int n0 = blockIdx.x * AGG_NPB + wave * AGG_NPW;   // grid exact
  int sv = 0;
  { int q = n0 + lane; if (lane <= AGG_NPW) sv = off[q]; }

  // preload all 4 nodes' first-64 edge indices
  int ev[AGG_NPW];
#pragma unroll
  for (int i = 0; i < AGG_NPW; i++) {
    int ks = __shfl(sv, i), ke = __shfl(sv, i + 1);
    int rem = ke - ks;
    ev[i] = (lane < rem) ? csr[ks + lane] : NN;
  }

  // ---- Phase 1: issue ALL first-batch gathers (16 loads, static names)
  uint4 v[AGG_NPW][4];
#pragma unroll
  for (int i = 0; i < AGG_NPW; i++) {
#pragma unroll
    for (int m = 0; m < 4; m++) {
      int nb = __shfl(ev[i], 4 * m + grp);   // pad slots give NN
      v[i][m] = *(const uint4*)((const char*)Abf + (((size_t)nb) << 8) + (p << 4));
    }
  }

  // ---- Phase 2: per-node consume (FULLY UNROLLED -> static v[i][m]) ----
#pragma unroll
  for (int i = 0; i < AGG_NPW; i++) {
    const int ks = __shfl(sv, i);
    const int ke = __shfl(sv, i + 1);
    const int deg = ke - ks;
    float acc[8] = {0.f, 0.f, 0.f, 0.f, 0.f, 0.f, 0.f, 0.f};
#pragma unroll
    for (int m = 0; m < 4; m++) {
      acc[0] += lo16f(v[i][m].x); acc[1] += hi16f(v[i][m].x);
      acc[2] += lo16f(v[i][m].y); acc[3] += hi16f(v[i][m].y);
      acc[4] += lo16f(v[i][m].z); acc[5] += hi16f(v[i][m].z);
      acc[6] += lo16f(v[i][m].w); acc[7] += hi16f(v[i][m].w);
    }
    // tail: edges 16..deg (15% of nodes; >64 ultra-rare)
#pragma unroll 1
    for (int c0 = 16; c0 < deg; c0 += 16) {
      uint4 w[4];
      if (c0 + 16 <= 64) {
#pragma unroll
        for (int m = 0; m < 4; m++) {
          int nb = __shfl(ev[i], c0 + 4 * m + grp);
          w[m] = *(const uint4*)((const char*)Abf + (((size_t)nb) << 8) + (p << 4));
        }
      } else {
        int rem2 = deg - c0;
        int evr = (lane < rem2) ? csr[ks + c0 + lane] : NN;
#pragma unroll
        for (int m = 0; m < 4; m++) {
          int nb = __shfl(evr, 4 * m + grp);
          w[m] = *(const uint4*)((const char*)Abf + (((size_t)nb) << 8) + (p << 4));
        }
      }
#pragma unroll
      for (int m = 0; m < 4; m++) {
        acc[0] += lo16f(w[m].x); acc[1] += hi16f(w[m].x);
        acc[2] += lo16f(w[m].y); acc[3] += hi16f(w[m].y);
        acc[4] += lo16f(w[m].z); acc[5] += hi16f(w[m].z);
        acc[6] += lo16f(w[m].w); acc[7] += hi16f(w[m].w);
      }
    }
    // combine the 4 lane-groups (disjoint neighbor subsets)
#pragma unroll
    for (int q = 0; q < 8; q++) {
      acc[q] += __shfl_xor(acc[q], 16);
      acc[q] += __shfl_xor(acc[q], 32);
    }
    const float dv = dinv[n0 + i];
    float o[8];
    o[0] = fmaf(acc[0], dv, bias03.x); o[1] = fmaf(acc[1], dv, bias03.y);
    o[2] = fmaf(acc[2], dv, bias03.z); o[3] = fmaf(acc[3], dv, bias03.w);
    o[4] = fmaf(acc[4], dv, bias47.x); o[5] = fmaf(acc[5], dv, bias47.y);
    o[6] = fmaf(acc[6], dv, bias47.z); o[7] = fmaf(acc[7], dv, bias47.w);
    if (grp == 0) {
      float4 w0 = make_float4(o[0], o[1], o[2], o[3]);
      float4 w1 = make_float4(o[4], o[5], o[6], o[7]);
      *(float4*)&B[(size_t)(n0 + i) * HD + p * 8] = w0;
      *(float4*)&B[(size_t)(n0 + i) * HD + p * 8 + 4] = w1;
#pragma unroll
      for (int q = 0; q < 8; q++) {
        atomicAdd(&sredb[p][q], o[q]);
        atomicAdd(&sredb[p][8 + q], o[q] * o[q]);
      }
    }
  }
  __syncthreads();
  {
    float* sp = stats + ((blockIdx.x & (NSC - 1)) << 8);   // 64-way scatter
    int pp = t >> 4, ii = t & 15;
    float v2 = sredb[pp][ii];
    atomicAddF(&sp[(ii < 8 ? 0 : 128) + pp * 8 + (ii & 7)], v2);
  }
}

// ---- GEMM (BN affine computed in-block from scattered stats) ----
#define GT_N 128
#define GT_KC 32
__global__ __launch_bounds__(256) void k_gemm(const float* __restrict__ Bin, const float* __restrict__ W,
                                              const float* __restrict__ stats, const float* __restrict__ gg,
                                              const float* __restrict__ be, const float* __restrict__ dinv,
                                              uint* __restrict__ Abf) {
  __shared__ float hs[GT_KC * 132];
  __shared__ float ws[GT_KC * 132];
  __shared__ float afl[128], cfl[128];
  const int t = threadIdx.x;
  if (t < 128) {
    float s1 = 0.f, s2 = 0.f;
#pragma unroll 4
    for (int i = 0; i < NSC; i++) {
      s1 += stats[i * 256 + t];
      s2 += stats[i * 256 + 128 + t];
    }
    float mean = s1 * (1.f / NN);
    float var = fmaxf(s2 * (1.f / NN) - mean * mean, 0.f);
    float inv = rsqrtf(var + EPSV);
    float a = gg[t] * inv;
    afl[t] = a;
    cfl[t] = be[t] - mean * a;
  }
  __syncthreads();

  const int base = blockIdx.x * GT_N;
  const int tx = t & 15, ty = t >> 4;
  float acc[8][8];
#pragma unroll
  for (int a = 0; a < 8; a++)
#pragma unroll
    for (int b = 0; b < 8; b++) acc[a][b] = 0.f;

  for (int k0 = 0; k0 < HD; k0 += GT_KC) {
    __syncthreads();
    {
      const float4* W4 = (const float4*)(W + k0 * HD);
#pragma unroll
      for (int i = t; i < 1024; i += 256) {
        int row = i >> 5, c4i = i & 31;
        float4 v = W4[i];
        *(float4*)&ws[row * 132 + c4i * 4] = v;
      }
    }
    {
#pragma unroll
      for (int i = t; i < 1024; i += 256) {
        int node = i >> 3, c4i = i & 7;
        int n = base + node;
        float4 v = make_float4(0.f, 0.f, 0.f, 0.f);
        if (n < NN) v = *(const float4*)&Bin[(size_t)n * HD + k0 + c4i * 4];
        int kk = c4i * 4;
        float r0 = fmaxf(fmaf(afl[k0 + kk + 0], v.x, cfl[k0 + kk + 0]), 0.f);
        float r1 = fmaxf(fmaf(afl[k0 + kk + 1], v.y, cfl[k0 + kk + 1]), 0.f);
        float r2 = fmaxf(fmaf(afl[k0 + kk + 2], v.z, cfl[k0 + kk + 2]), 0.f);
        float r3 = fmaxf(fmaf(afl[k0 + kk + 3], v.w, cfl[k0 + kk + 3]), 0.f);
        hs[(kk + 0) * 132 + node] = r0;
        hs[(kk + 1) * 132 + node] = r1;
        hs[(kk + 2) * 132 + node] = r2;
        hs[(kk + 3) * 132 + node] = r3;
      }
    }
    __syncthreads();
#pragma unroll
    for (int k = 0; k < GT_KC; k++) {
      float4 h0 = *(float4*)&hs[k * 132 + ty * 8];
      float4 h1 = *(float4*)&hs[k * 132 + ty * 8 + 4];
      float4 w0 = *(float4*)&ws[k * 132 + tx * 8];
      float4 w1 = *(float4*)&ws[k * 132 + tx * 8 + 4];
      float hh[8] = {h0.x, h0.y, h0.z, h0.w, h1.x, h1.y, h1.z, h1.w};
      float wv[8] = {w0.x, w0.y, w0.z, w0.w, w1.x, w1.y, w1.z, w1.w};
#pragma unroll
      for (int a = 0; a < 8; a++)
#pragma unroll
        for (int b = 0; b < 8; b++) acc[a][b] = fmaf(hh[a], wv[b], acc[a][b]);
    }
  }
#pragma unroll
  for (int a = 0; a < 8; a++) {
    int n = base + ty * 8 + a;
    if (n < NN) {
      float s = dinv[n];
      uint4 o;
      o.x = pack2bf(acc[a][0] * s, acc[a][1] * s);
      o.y = pack2bf(acc[a][2] * s, acc[a][3] * s);
      o.z = pack2bf(acc[a][4] * s, acc[a][5] * s);
      o.w = pack2bf(acc[a][6] * s, acc[a][7] * s);
      *(uint4*)&Abf[(size_t)n * 64 + tx * 4] = o;
    }
  }
}

// ---- pool + FC (affine folded in; 2 node-lanes x 128 features) ----
__global__ __launch_bounds__(256) void k_pool(const float* __restrict__ B, const float* __restrict__ stats,
                                              const float* __restrict__ gg, const float* __restrict__ be,
                                              const int* __restrict__ gstart,
                                              const float* __restrict__ fcW, const float* __restrict__ fcb,
                                              float* __restrict__ out) {
  __shared__ float afl[128], cfl[128];
  int t = threadIdx.x;
  if (t < 128) {
    float s1 = 0.f, s2 = 0.f;
#pragma unroll 4
    for (int i = 0; i < NSC; i++) {
      s1 += stats[i * 256 + t];
      s2 += stats[i * 256 + 128 + t];
    }
    float mean = s1 * (1.f / NN);
    float var = fmaxf(s2 * (1.f / NN) - mean * mean, 0.f);
    float inv = rsqrtf(var + EPSV);
    float a = gg[t] * inv;
    afl[t] = a;
    cfl[t] = be[t] - mean * a;
  }
  __syncthreads();

  int g = blockIdx.x;
  int r = t >> 7, f = t & 127;
  int gs = gstart[g], ge = gstart[g + 1];
  float a = afl[f], c = cfl[f];
  float a0 = 0.f, a1 = 0.f, a2 = 0.f, a3 = 0.f;
  int n = gs + r;
  for (; n + 6 < ge; n += 8) {
    a0 += fmaxf(fmaf(a, B[(size_t)(n + 0) * HD + f], c), 0.f);
    a1 += fmaxf(fmaf(a, B[(size_t)(n + 2) * HD + f], c), 0.f);
    a2 += fmaxf(fmaf(a, B[(size_t)(n + 4) * HD + f], c), 0.f);
    a3 += fmaxf(fmaf(a, B[(size_t)(n + 6) * HD + f], c), 0.f);
  }
  for (; n < ge; n += 2) a0 += fmaxf(fmaf(a, B[(size_t)n * HD + f], c), 0.f);
  float acc = (a0 + a1) + (a2 + a3);
  __shared__ float lp[256];
  lp[t] = acc;
  __syncthreads();
  if (r == 0) {
    float pooled = (lp[f] + lp[f + 128]) / fmaxf((float)(ge - gs), 1.f);
    lp[f] = pooled;
  }
  __syncthreads();
  if (t < 3) {
    float o = fcb[t];
    for (int k = 0; k < 128; k++) o += lp[k] * fcW[k * 3 + t];
    out[g * 3 + t] = o;
  }
}

extern "C" void kernel_launch(void* const* d_in, const int* in_sizes, int n_in,
                              void* d_out, int out_size, void* d_ws, size_t ws_size,
                              hipStream_t stream) {
  const float* x    = (const float*)d_in[0];
  const int* ei     = (const int*)d_in[1];
  const int* batch  = (const int*)d_in[2];
  const float* emb0 = (const float*)d_in[3];
  const float* emb1 = (const float*)d_in[4];
  const float* emb2 = (const float*)d_in[5];
  const float* emb5 = (const float*)d_in[6];
  const float* W1   = (const float*)d_in[7];
  const float* b1   = (const float*)d_in[8];
  const float* W2   = (const float*)d_in[9];
  const float* b2   = (const float*)d_in[10];
  const float* W3   = (const float*)d_in[11];
  const float* b3   = (const float*)d_in[12];
  const float* g1   = (const float*)d_in[13];
  const float* be1  = (const float*)d_in[14];
  const float* g2   = (const float*)d_in[15];
  const float* be2  = (const float*)d_in[16];
  const float* g3   = (const float*)d_in[17];
  const float* be3  = (const float*)d_in[18];
  const float* fcW  = (const float*)d_in[19];
  const float* fcb  = (const float*)d_in[20];
  float* out = (float*)d_out;

  const int* esrc = ei;
  const int* edst = ei + NE;

  char* p = (char*)d_ws;
  size_t o = 0;
  auto alloc = [&](size_t bytes) -> void* {
    o = (o + 255) & ~(size_t)255;
    void* r = p + o;
    o += bytes;
    return r;
  };
  int* cnt      = (int*)alloc(NN * 4);
  float* stats  = (float*)alloc(3 * NSC * 256 * 4);   // 3 layers x 64 copies x (sum,sumsq)
  size_t zbytes = o;                                  // memset covers cnt+stats
  int* off      = (int*)alloc((NN + 1) * 4);
  int* cursor   = (int*)alloc(NN * 4);
  int* csr      = (int*)alloc((size_t)(NE + NN + 64) * 4);
  float* dinv   = (float*)alloc(NN * 4);
  float* tabs   = (float*)alloc(470 * HD * 4);
  float* row0   = (float*)alloc(HD * 4);
  int* gstart   = (int*)alloc((NG + 1) * 4);
  int* partials = (int*)alloc(16 * 4);
  uint* Abf     = (uint*)alloc((size_t)(NN + 1) * 64 * 4);   // 256B bf16 rows (+pad row)
  float* bufB   = (float*)alloc((size_t)NN * HD * 4);
  (void)ws_size; (void)n_in; (void)in_sizes; (void)out_size;

  hipMemsetAsync(d_ws, 0, zbytes, stream);

  k_pro1<<<2818, 256, 0, stream>>>(edst, cnt, emb0, emb1, emb2, emb5, W1, tabs, row0, batch, gstart);
  k_scanA<<<13, 1024, 0, stream>>>(cnt, partials);
  k_scanB<<<1, 64, 0, stream>>>(partials, off);
  k_scanC<<<13, 1024, 0, stream>>>(cnt, partials, off, cursor, dinv, csr, Abf);
  k_pro2<<<14844, 256, 0, stream>>>(esrc, edst, cursor, csr, x, (const float2*)tabs,
                                    (const float2*)row0, dinv, Abf);

  const int nagg = NN / AGG_NPB;            // 3125, exact
  const int ngemm = (NN + GT_N - 1) / GT_N;
  float* st1 = stats;
  float* st2 = stats + NSC * 256;
  float* st3 = stats + 2 * NSC * 256;

  // layer 1
  k_agg<<<nagg, 256, 0, stream>>>(Abf, off, csr, dinv, b1, bufB, st1);
  // layer 2
  k_gemm<<<ngemm, 256, 0, stream>>>(bufB, W2, st1, g1, be1, dinv, Abf);
  k_agg<<<nagg, 256, 0, stream>>>(Abf, off, csr, dinv, b2, bufB, st2);
  // layer 3
  k_gemm<<<ngemm, 256, 0, stream>>>(bufB, W3, st2, g2, be2, dinv, Abf);
  k_agg<<<nagg, 256, 0, stream>>>(Abf, off, csr, dinv, b3, bufB, st3);
  // pool + fc
  k_pool<<<NG, 256, 0, stream>>>(bufB, st3, g3, be3, gstart, fcW, fcb, out);
}

// Round 14
// 414.367 us; speedup vs baseline: 1.1773x; 1.0753x over previous
//
#include <hip/hip_runtime.h>

#define NN 50000
#define NE 600000
#define NG 512
#define HD 128
#define EPSV 1e-5f
#define NSC 64                    // stats scatter copies

typedef unsigned int uint;
typedef __attribute__((ext_vector_type(8))) short short8;
typedef __attribute__((ext_vector_type(4))) float f32x4;

__device__ inline void atomicAddF(float* p, float v) {
  __hip_atomic_fetch_add(p, v, __ATOMIC_RELAXED, __HIP_MEMORY_SCOPE_AGENT);
}

__device__ inline uint bf16rne(float f) {
  uint u = __float_as_uint(f);
  return (u + 0x7fffu + ((u >> 16) & 1u)) >> 16;
}
__device__ inline uint pack2bf(float a, float b) {
  return bf16rne(a) | (bf16rne(b) << 16);
}
__device__ inline float lo16f(uint u) { return __uint_as_float(u << 16); }
__device__ inline float hi16f(uint u) { return __uint_as_float(u & 0xffff0000u); }

// ---- prologue 1: count (0..2343) + tabs (2344..2814) + bsearch (2815..2817)
//      + W2->Wbt2 (2818..2833) + W3->Wbt3 (2834..2849)
__global__ __launch_bounds__(256) void k_pro1(const int* __restrict__ dst, int* __restrict__ cnt,
                                              const float* __restrict__ emb0, const float* __restrict__ emb1,
                                              const float* __restrict__ emb2, const float* __restrict__ emb5,
                                              const float* __restrict__ W1, float* __restrict__ tabs,
                                              float* __restrict__ row0, const int* __restrict__ batch,
                                              int* __restrict__ gstart,
                                              const float* __restrict__ W2, const float* __restrict__ W3,
                                              uint* __restrict__ Wbt2, uint* __restrict__ Wbt3) {
  const int bid = blockIdx.x, t = threadIdx.x;
  if (bid < 2344) {
    int e = bid * 256 + t;
    if (e < NE) atomicAdd(&cnt[dst[e]], 1);
    return;
  }
  if (bid < 2815) {
    if (t >= 128) return;
    int r = bid - 2344, f = t;
    if (r == 470) { row0[f] = W1[f]; return; }
    const float* e;
    int wbase;
    if (r < 96)      { e = emb0 + r * 32;         wbase = 1;  }
    else if (r < 192){ e = emb1 + (r - 96) * 32;  wbase = 33; }
    else if (r < 288){ e = emb2 + (r - 192) * 32; wbase = 65; }
    else             { e = emb5 + (r - 288) * 32; wbase = 97; }
    float acc = 0.f;
#pragma unroll 8
    for (int k = 0; k < 32; k++) acc += e[k] * W1[(wbase + k) * HD + f];
    tabs[r * HD + f] = acc;
    return;
  }
  if (bid < 2818) {
    int g = (bid - 2815) * 256 + t;
    if (g > NG) return;
    if (g == NG) { gstart[NG] = NN; return; }
    int lo = 0, hi = NN;
    while (lo < hi) {
      int mid = (lo + hi) >> 1;
      if (batch[mid] < g) lo = mid + 1;
      else hi = mid;
    }
    gstart[g] = lo;
    return;
  }
  {
    // W transpose+bf16: Wbt[f][k] = bf16(W[k][f]); 16 blocks per matrix
    const float* W = (bid < 2834) ? W2 : W3;
    uint* Wbt = (bid < 2834) ? Wbt2 : Wbt3;
    int b = (bid < 2834) ? (bid - 2818) : (bid - 2834);
    int f = b * 8 + (t >> 5);
    int kq = (t & 31) * 4;
    float w0 = W[(kq + 0) * HD + f];
    float w1 = W[(kq + 1) * HD + f];
    float w2 = W[(kq + 2) * HD + f];
    float w3 = W[(kq + 3) * HD + f];
    Wbt[f * 64 + (t & 31) * 2 + 0] = pack2bf(w0, w1);
    Wbt[f * 64 + (t & 31) * 2 + 1] = pack2bf(w2, w3);
  }
}

// ---- 3-phase scan over deg+1 (tile = 4096 elems/block, 13 blocks) ----
__global__ __launch_bounds__(1024) void k_scanA(const int* __restrict__ cnt, int* __restrict__ partials) {
  int t = threadIdx.x;
  int i0 = blockIdx.x * 4096 + 4 * t;
  int s = 0;
#pragma unroll
  for (int j = 0; j < 4; j++) {
    int idx = i0 + j;
    s += (idx < NN) ? (cnt[idx] + 1) : 0;
  }
#pragma unroll
  for (int d = 1; d < 64; d <<= 1) s += __shfl_xor(s, d);
  __shared__ int wsum[16];
  if ((t & 63) == 0) wsum[t >> 6] = s;
  __syncthreads();
  if (t == 0) {
    int tot = 0;
#pragma unroll
    for (int i = 0; i < 16; i++) tot += wsum[i];
    partials[blockIdx.x] = tot;
  }
}

__global__ __launch_bounds__(64) void k_scanB(int* __restrict__ partials, int* __restrict__ off) {
  if (threadIdx.x == 0) {
    int acc = 0;
#pragma unroll
    for (int i = 0; i < 13; i++) { int v = partials[i]; partials[i] = acc; acc += v; }
    partials[13] = acc;
    off[NN] = acc;
  }
}

__global__ __launch_bounds__(1024) void k_scanC(const int* __restrict__ cnt, const int* __restrict__ partials,
                                                int* __restrict__ off, int* __restrict__ cursor,
                                                float* __restrict__ dinv, int* __restrict__ csr,
                                                uint* __restrict__ Abf) {
  __shared__ int part[16];
  __shared__ int partscan[16];
  int t = threadIdx.x;
  int lane = t & 63, w = t >> 6;
  if (blockIdx.x == 0 && t < 64) {
    Abf[(size_t)NN * 64 + t] = 0u;   // zero pad row (256B bf16 row = 64 uints)
  }
  int i0 = blockIdx.x * 4096 + 4 * t;
  int c[4], v[4];
#pragma unroll
  for (int j = 0; j < 4; j++) {
    int idx = i0 + j;
    c[j] = (idx < NN) ? cnt[idx] : 0;
    v[j] = (idx < NN) ? (c[j] + 1) : 0;
  }
  int tsum = (v[0] + v[1]) + (v[2] + v[3]);
  int val = tsum;
#pragma unroll
  for (int s = 1; s < 64; s <<= 1) {
    int u = __shfl_up(val, s);
    if (lane >= s) val += u;
  }
  if (lane == 63) part[w] = val;
  __syncthreads();
  if (t == 0) {
    int acc = 0;
#pragma unroll
    for (int i = 0; i < 16; i++) { acc += part[i]; partscan[i] = acc; }
  }
  __syncthreads();
  int waveoff = (w > 0) ? partscan[w - 1] : 0;
  int run = val - tsum + waveoff + partials[blockIdx.x];
#pragma unroll
  for (int j = 0; j < 4; j++) {
    int idx = i0 + j;
    if (idx < NN) {
      off[idx] = run;
      cursor[idx] = run + 1;
      csr[run] = idx;                        // self-edge
      dinv[idx] = rsqrtf((float)c[j] + 1.0f);
      run += v[j];
    }
  }
}

// ---- prologue 2: fill (blocks 0..2343) + embed (2344..14843) ----
__global__ __launch_bounds__(256) void k_pro2(const int* __restrict__ src, const int* __restrict__ dst,
                                              int* __restrict__ cursor, int* __restrict__ csr,
                                              const float* __restrict__ x, const float2* __restrict__ tabs2,
                                              const float2* __restrict__ row02, const float* __restrict__ dinv,
                                              uint* __restrict__ Abf) {
  const int bid = blockIdx.x, t = threadIdx.x;
  if (bid < 2344) {
    int e = bid * 256 + t;
    if (e < NE) {
      int p = atomicAdd(&cursor[dst[e]], 1);
      csr[p] = src[e];
    }
    return;
  }
  int n = (bid - 2344) * 4 + (t >> 6);   // exact: 12500*4 = NN
  int lane = t & 63;
  float poss = x[n * 5 + 0];
  int i0 = (int)x[n * 5 + 1];
  int i1 = (int)x[n * 5 + 2];
  int i2 = (int)x[n * 5 + 3];
  int i5 = (int)x[n * 5 + 4];
  float2 r0 = row02[lane];
  float2 t0 = tabs2[(size_t)i0 * 64 + lane];
  float2 t1 = tabs2[(size_t)(96 + i1) * 64 + lane];
  float2 t2 = tabs2[(size_t)(192 + i2) * 64 + lane];
  float2 t5 = tabs2[(size_t)(288 + i5) * 64 + lane];
  float hx = poss * r0.x + t0.x + t1.x + t2.x + t5.x;
  float hy = poss * r0.y + t0.y + t1.y + t2.y + t5.y;
  float dv = dinv[n];
  Abf[(size_t)n * 64 + lane] = pack2bf(hx * dv, hy * dv);
}

// ---- aggregation (r10 winner structure); B output now packed bf16 ----
#define AGG_NPW 4
#define AGG_NPB (4 * AGG_NPW)
__global__ __launch_bounds__(256) void k_agg(const uint* __restrict__ Abf, const int* __restrict__ off,
                                             const int* __restrict__ csr, const float* __restrict__ dinv,
                                             const float* __restrict__ bias, uint* __restrict__ Bbf,
                                             float* __restrict__ stats) {
  const int t = threadIdx.x, lane = t & 63, wave = t >> 6;
  const int grp = lane >> 4, p = lane & 15;
  __shared__ float sredb[16][17];   // [p][8 sums + 8 sumsqs], padded
  for (int q = t; q < 16 * 17; q += 256) ((float*)sredb)[q] = 0.f;
  __syncthreads();

  const float4 bias03 = ((const float4*)bias)[p * 2];
  const float4 bias47 = ((const float4*)bias)[p * 2 + 1];

  const int n0 = blockIdx.x * AGG_NPB + wave * AGG_NPW;   // grid exact
  int sv = 0;
  { int q = n0 + lane; if (lane <= AGG_NPW) sv = off[q]; }

  // preload all 4 nodes' first-64 edge indices
  int ev[AGG_NPW];
#pragma unroll
  for (int i = 0; i < AGG_NPW; i++) {
    int ks = __shfl(sv, i), ke = __shfl(sv, i + 1);
    int rem = ke - ks;
    ev[i] = (lane < rem) ? csr[ks + lane] : NN;
  }

  // ---- Phase 1: issue ALL first-batch gathers (16 loads, static names)
  uint4 v[AGG_NPW][4];
#pragma unroll
  for (int i = 0; i < AGG_NPW; i++) {
#pragma unroll
    for (int m = 0; m < 4; m++) {
      int nb = __shfl(ev[i], 4 * m + grp);   // pad slots give NN
      v[i][m] = *(const uint4*)((const char*)Abf + (((size_t)nb) << 8) + (p << 4));
    }
  }

  // ---- Phase 2: per-node consume (FULLY UNROLLED -> static v[i][m]) ----
#pragma unroll
  for (int i = 0; i < AGG_NPW; i++) {
    const int ks = __shfl(sv, i);
    const int ke = __shfl(sv, i + 1);
    const int deg = ke - ks;
    float acc[8] = {0.f, 0.f, 0.f, 0.f, 0.f, 0.f, 0.f, 0.f};
#pragma unroll
    for (int m = 0; m < 4; m++) {
      acc[0] += lo16f(v[i][m].x); acc[1] += hi16f(v[i][m].x);
      acc[2] += lo16f(v[i][m].y); acc[3] += hi16f(v[i][m].y);
      acc[4] += lo16f(v[i][m].z); acc[5] += hi16f(v[i][m].z);
      acc[6] += lo16f(v[i][m].w); acc[7] += hi16f(v[i][m].w);
    }
    // tail: edges 16..deg (15% of nodes; >64 ultra-rare)
#pragma unroll 1
    for (int c0 = 16; c0 < deg; c0 += 16) {
      uint4 w[4];
      if (c0 + 16 <= 64) {
#pragma unroll
        for (int m = 0; m < 4; m++) {
          int nb = __shfl(ev[i], c0 + 4 * m + grp);
          w[m] = *(const uint4*)((const char*)Abf + (((size_t)nb) << 8) + (p << 4));
        }
      } else {
        int rem2 = deg - c0;
        int evr = (lane < rem2) ? csr[ks + c0 + lane] : NN;
#pragma unroll
        for (int m = 0; m < 4; m++) {
          int nb = __shfl(evr, 4 * m + grp);
          w[m] = *(const uint4*)((const char*)Abf + (((size_t)nb) << 8) + (p << 4));
        }
      }
#pragma unroll
      for (int m = 0; m < 4; m++) {
        acc[0] += lo16f(w[m].x); acc[1] += hi16f(w[m].x);
        acc[2] += lo16f(w[m].y); acc[3] += hi16f(w[m].y);
        acc[4] += lo16f(w[m].z); acc[5] += hi16f(w[m].z);
        acc[6] += lo16f(w[m].w); acc[7] += hi16f(w[m].w);
      }
    }
    // combine the 4 lane-groups (disjoint neighbor subsets)
#pragma unroll
    for (int q = 0; q < 8; q++) {
      acc[q] += __shfl_xor(acc[q], 16);
      acc[q] += __shfl_xor(acc[q], 32);
    }
    const float dv = dinv[n0 + i];
    float o[8];
    o[0] = fmaf(acc[0], dv, bias03.x); o[1] = fmaf(acc[1], dv, bias03.y);
    o[2] = fmaf(acc[2], dv, bias03.z); o[3] = fmaf(acc[3], dv, bias03.w);
    o[4] = fmaf(acc[4], dv, bias47.x); o[5] = fmaf(acc[5], dv, bias47.y);
    o[6] = fmaf(acc[6], dv, bias47.z); o[7] = fmaf(acc[7], dv, bias47.w);
    if (grp == 0) {
      uint4 ob;
      ob.x = pack2bf(o[0], o[1]);
      ob.y = pack2bf(o[2], o[3]);
      ob.z = pack2bf(o[4], o[5]);
      ob.w = pack2bf(o[6], o[7]);
      *(uint4*)&Bbf[(size_t)(n0 + i) * 64 + p * 4] = ob;
#pragma unroll
      for (int q = 0; q < 8; q++) {
        atomicAdd(&sredb[p][q], o[q]);
        atomicAdd(&sredb[p][8 + q], o[q] * o[q]);
      }
    }
  }
  __syncthreads();
  {
    float* sp = stats + ((blockIdx.x & (NSC - 1)) << 8);   // 64-way scatter
    int pp = t >> 4, ii = t & 15;
    float v2 = sredb[pp][ii];
    atomicAddF(&sp[(ii < 8 ? 0 : 128) + pp * 8 + (ii & 7)], v2);
  }
}

// ---- GEMM via MFMA bf16: Abf = bf16(dinv * (relu(affine(Bbf)) @ W)) ----
// 128-node tile, 4 waves; wave (w&1)=node-half, (w>>1)=f-half; K chunked by 64.
__global__ __launch_bounds__(256) void k_gemm(const uint* __restrict__ Bbf, const uint* __restrict__ Wbt,
                                              const float* __restrict__ stats, const float* __restrict__ gg,
                                              const float* __restrict__ be, const float* __restrict__ dinv,
                                              uint* __restrict__ Abf) {
  __shared__ uint hs[128 * 33];
  __shared__ uint ws[128 * 33];
  __shared__ float afl[128], cfl[128], dvl[128];
  const int t = threadIdx.x;
  const int base = blockIdx.x * 128;
  if (t < 128) {
    float s1 = 0.f, s2 = 0.f;
#pragma unroll 4
    for (int i = 0; i < NSC; i++) {
      s1 += stats[i * 256 + t];
      s2 += stats[i * 256 + 128 + t];
    }
    float mean = s1 * (1.f / NN);
    float var = fmaxf(s2 * (1.f / NN) - mean * mean, 0.f);
    float inv = rsqrtf(var + EPSV);
    float a = gg[t] * inv;
    afl[t] = a;
    cfl[t] = be[t] - mean * a;
    int gn = base + t;
    dvl[t] = (gn < NN) ? dinv[gn] : 0.f;
  }

  const int lane = t & 63, wave = t >> 6;
  const int r16 = lane & 15, hi = lane >> 4;
  const int nb = (wave & 1) * 64, fb = (wave >> 1) * 64;

  f32x4 acc00 = {0.f,0.f,0.f,0.f}, acc01 = acc00, acc02 = acc00, acc03 = acc00;
  f32x4 acc10 = acc00, acc11 = acc00, acc12 = acc00, acc13 = acc00;
  f32x4 acc20 = acc00, acc21 = acc00, acc22 = acc00, acc23 = acc00;
  f32x4 acc30 = acc00, acc31 = acc00, acc32 = acc00, acc33 = acc00;

#pragma unroll
  for (int kc = 0; kc < 2; kc++) {
    __syncthreads();
    // stage hs: 128 nodes x 32 uints (k = kc*64 .. +63), affine+relu fused
#pragma unroll
    for (int it = 0; it < 4; it++) {
      int idx = t + it * 256;            // 0..1023
      int n = idx >> 3, c4 = idx & 7;
      int gn = base + n;
      uint4 vv = make_uint4(0u, 0u, 0u, 0u);
      if (gn < NN) vv = *(const uint4*)&Bbf[(size_t)gn * 64 + kc * 32 + c4 * 4];
      int k0 = kc * 64 + c4 * 8;
      uint r0 = pack2bf(fmaxf(fmaf(afl[k0+0], lo16f(vv.x), cfl[k0+0]), 0.f),
                        fmaxf(fmaf(afl[k0+1], hi16f(vv.x), cfl[k0+1]), 0.f));
      uint r1 = pack2bf(fmaxf(fmaf(afl[k0+2], lo16f(vv.y), cfl[k0+2]), 0.f),
                        fmaxf(fmaf(afl[k0+3], hi16f(vv.y), cfl[k0+3]), 0.f));
      uint r2 = pack2bf(fmaxf(fmaf(afl[k0+4], lo16f(vv.z), cfl[k0+4]), 0.f),
                        fmaxf(fmaf(afl[k0+5], hi16f(vv.z), cfl[k0+5]), 0.f));
      uint r3 = pack2bf(fmaxf(fmaf(afl[k0+6], lo16f(vv.w), cfl[k0+6]), 0.f),
                        fmaxf(fmaf(afl[k0+7], hi16f(vv.w), cfl[k0+7]), 0.f));
      hs[n * 33 + c4 * 4 + 0] = r0;
      hs[n * 33 + c4 * 4 + 1] = r1;
      hs[n * 33 + c4 * 4 + 2] = r2;
      hs[n * 33 + c4 * 4 + 3] = r3;
    }
    // stage ws: 128 f x 32 uints
#pragma unroll
    for (int it = 0; it < 4; it++) {
      int idx = t + it * 256;
      int f = idx >> 3, c4 = idx & 7;
      uint4 vv = *(const uint4*)&Wbt[(size_t)f * 64 + kc * 32 + c4 * 4];
      *(uint4*)&ws[f * 33 + c4 * 4] = vv;
    }
    __syncthreads();
#pragma unroll
    for (int ksl = 0; ksl < 2; ksl++) {
      int ko = ksl * 16 + hi * 4;
      short8 a0 = *(short8*)&hs[(nb + 0 * 16 + r16) * 33 + ko];
      short8 a1 = *(short8*)&hs[(nb + 1 * 16 + r16) * 33 + ko];
      short8 a2 = *(short8*)&hs[(nb + 2 * 16 + r16) * 33 + ko];
      short8 a3 = *(short8*)&hs[(nb + 3 * 16 + r16) * 33 + ko];
      short8 b0 = *(short8*)&ws[(fb + 0 * 16 + r16) * 33 + ko];
      short8 b1 = *(short8*)&ws[(fb + 1 * 16 + r16) * 33 + ko];
      short8 b2 = *(short8*)&ws[(fb + 2 * 16 + r16) * 33 + ko];
      short8 b3 = *(short8*)&ws[(fb + 3 * 16 + r16) * 33 + ko];
      acc00 = __builtin_amdgcn_mfma_f32_16x16x32_bf16(a0, b0, acc00, 0, 0, 0);
      acc01 = __builtin_amdgcn_mfma_f32_16x16x32_bf16(a0, b1, acc01, 0, 0, 0);
      acc02 = __builtin_amdgcn_mfma_f32_16x16x32_bf16(a0, b2, acc02, 0, 0, 0);
      acc03 = __builtin_amdgcn_mfma_f32_16x16x32_bf16(a0, b3, acc03, 0, 0, 0);
      acc10 = __builtin_amdgcn_mfma_f32_16x16x32_bf16(a1, b0, acc10, 0, 0, 0);
      acc11 = __builtin_amdgcn_mfma_f32_16x16x32_bf16(a1, b1, acc11, 0, 0, 0);
      acc12 = __builtin_amdgcn_mfma_f32_16x16x32_bf16(a1, b2, acc12, 0, 0, 0);
      acc13 = __builtin_amdgcn_mfma_f32_16x16x32_bf16(a1, b3, acc13, 0, 0, 0);
      acc20 = __builtin_amdgcn_mfma_f32_16x16x32_bf16(a2, b0, acc20, 0, 0, 0);
      acc21 = __builtin_amdgcn_mfma_f32_16x16x32_bf16(a2, b1, acc21, 0, 0, 0);
      acc22 = __builtin_amdgcn_mfma_f32_16x16x32_bf16(a2, b2, acc22, 0, 0, 0);
      acc23 = __builtin_amdgcn_mfma_f32_16x16x32_bf16(a2, b3, acc23, 0, 0, 0);
      acc30 = __builtin_amdgcn_mfma_f32_16x16x32_bf16(a3, b0, acc30, 0, 0, 0);
      acc31 = __builtin_amdgcn_mfma_f32_16x16x32_bf16(a3, b1, acc31, 0, 0, 0);
      acc32 = __builtin_amdgcn_mfma_f32_16x16x32_bf16(a3, b2, acc32, 0, 0, 0);
      acc33 = __builtin_amdgcn_mfma_f32_16x16x32_bf16(a3, b3, acc33, 0, 0, 0);
    }
  }

  // epilogue: C mapping col=lane&15 (f), row=(lane>>4)*4+reg (node) [m89]
  unsigned short* A16 = (unsigned short*)Abf;
#define STORE_TILE(ACC, M, N) { \
    _Pragma("unroll") \
    for (int reg = 0; reg < 4; reg++) { \
      int nl = nb + (M) * 16 + hi * 4 + reg; \
      int gn = base + nl; \
      if (gn < NN) { \
        float val = ACC[reg] * dvl[nl]; \
        A16[(size_t)gn * 128 + fb + (N) * 16 + r16] = (unsigned short)bf16rne(val); \
      } \
    } }
  STORE_TILE(acc00, 0, 0) STORE_TILE(acc01, 0, 1) STORE_TILE(acc02, 0, 2) STORE_TILE(acc03, 0, 3)
  STORE_TILE(acc10, 1, 0) STORE_TILE(acc11, 1, 1) STORE_TILE(acc12, 1, 2) STORE_TILE(acc13, 1, 3)
  STORE_TILE(acc20, 2, 0) STORE_TILE(acc21, 2, 1) STORE_TILE(acc22, 2, 2) STORE_TILE(acc23, 2, 3)
  STORE_TILE(acc30, 3, 0) STORE_TILE(acc31, 3, 1) STORE_TILE(acc32, 3, 2) STORE_TILE(acc33, 3, 3)
#undef STORE_TILE
}

// ---- pool + FC (affine folded in; bf16 input; 2 node-lanes x 128 features) ----
__global__ __launch_bounds__(256) void k_pool(const uint* __restrict__ Bbf, const float* __restrict__ stats,
                                              const float* __restrict__ gg, const float* __restrict__ be,
                                              const int* __restrict__ gstart,
                                              const float* __restrict__ fcW, const float* __restrict__ fcb,
                                              float* __restrict__ out) {
  __shared__ float afl[128], cfl[128];
  int t = threadIdx.x;
  if (t < 128) {
    float s1 = 0.f, s2 = 0.f;
#pragma unroll 4
    for (int i = 0; i < NSC; i++) {
      s1 += stats[i * 256 + t];
      s2 += stats[i * 256 + 128 + t];
    }
    float mean = s1 * (1.f / NN);
    float var = fmaxf(s2 * (1.f / NN) - mean * mean, 0.f);
    float inv = rsqrtf(var + EPSV);
    float a = gg[t] * inv;
    afl[t] = a;
    cfl[t] = be[t] - mean * a;
  }
  __syncthreads();

  int g = blockIdx.x;
  int r = t >> 7, f = t & 127;
  int gs = gstart[g], ge = gstart[g + 1];
  float a = afl[f], c = cfl[f];
  int half = f >> 1;   // uint index within 64-uint row
  int odd = f & 1;
  float a0 = 0.f, a1 = 0.f, a2 = 0.f, a3 = 0.f;
  int n = gs + r;
  for (; n + 6 < ge; n += 8) {
    uint u0 = Bbf[(size_t)(n + 0) * 64 + half];
    uint u1 = Bbf[(size_t)(n + 2) * 64 + half];
    uint u2 = Bbf[(size_t)(n + 4) * 64 + half];
    uint u3 = Bbf[(size_t)(n + 6) * 64 + half];
    a0 += fmaxf(fmaf(a, odd ? hi16f(u0) : lo16f(u0), c), 0.f);
    a1 += fmaxf(fmaf(a, odd ? hi16f(u1) : lo16f(u1), c), 0.f);
    a2 += fmaxf(fmaf(a, odd ? hi16f(u2) : lo16f(u2), c), 0.f);
    a3 += fmaxf(fmaf(a, odd ? hi16f(u3) : lo16f(u3), c), 0.f);
  }
  for (; n < ge; n += 2) {
    uint u0 = Bbf[(size_t)n * 64 + half];
    a0 += fmaxf(fmaf(a, odd ? hi16f(u0) : lo16f(u0), c), 0.f);
  }
  float acc = (a0 + a1) + (a2 + a3);
  __shared__ float lp[256];
  lp[t] = acc;
  __syncthreads();
  if (r == 0) {
    float pooled = (lp[f] + lp[f + 128]) / fmaxf((float)(ge - gs), 1.f);
    lp[f] = pooled;
  }
  __syncthreads();
  if (t < 3) {
    float o = fcb[t];
    for (int k = 0; k < 128; k++) o += lp[k] * fcW[k * 3 + t];
    out[g * 3 + t] = o;
  }
}

extern "C" void kernel_launch(void* const* d_in, const int* in_sizes, int n_in,
                              void* d_out, int out_size, void* d_ws, size_t ws_size,
                              hipStream_t stream) {
  const float* x    = (const float*)d_in[0];
  const int* ei     = (const int*)d_in[1];
  const int* batch  = (const int*)d_in[2];
  const float* emb0 = (const float*)d_in[3];
  const float* emb1 = (const float*)d_in[4];
  const float* emb2 = (const float*)d_in[5];
  const float* emb5 = (const float*)d_in[6];
  const float* W1   = (const float*)d_in[7];
  const float* b1   = (const float*)d_in[8];
  const float* W2   = (const float*)d_in[9];
  const float* b2   = (const float*)d_in[10];
  const float* W3   = (const float*)d_in[11];
  const float* b3   = (const float*)d_in[12];
  const float* g1   = (const float*)d_in[13];
  const float* be1  = (const float*)d_in[14];
  const float* g2   = (const float*)d_in[15];
  const float* be2  = (const float*)d_in[16];
  const float* g3   = (const float*)d_in[17];
  const float* be3  = (const float*)d_in[18];
  const float* fcW  = (const float*)d_in[19];
  const float* fcb  = (const float*)d_in[20];
  float* out = (float*)d_out;

  const int* esrc = ei;
  const int* edst = ei + NE;

  char* p = (char*)d_ws;
  size_t o = 0;
  auto alloc = [&](size_t bytes) -> void* {
    o = (o + 255) & ~(size_t)255;
    void* r = p + o;
    o += bytes;
    return r;
  };
  int* cnt      = (int*)alloc(NN * 4);
  float* stats  = (float*)alloc(3 * NSC * 256 * 4);   // 3 layers x 64 copies x (sum,sumsq)
  size_t zbytes = o;                                  // memset covers cnt+stats
  int* off      = (int*)alloc((NN + 1) * 4);
  int* cursor   = (int*)alloc(NN * 4);
  int* csr      = (int*)alloc((size_t)(NE + NN + 64) * 4);
  float* dinv   = (float*)alloc(NN * 4);
  float* tabs   = (float*)alloc(470 * HD * 4);
  float* row0   = (float*)alloc(HD * 4);
  int* gstart   = (int*)alloc((NG + 1) * 4);
  int* partials = (int*)alloc(16 * 4);
  uint* Abf     = (uint*)alloc((size_t)(NN + 1) * 64 * 4);   // 256B bf16 rows (+pad row)
  uint* Bbf     = (uint*)alloc((size_t)NN * 64 * 4);         // bf16 agg output
  uint* Wbt2    = (uint*)alloc(128 * 64 * 4);
  uint* Wbt3    = (uint*)alloc(128 * 64 * 4);
  (void)ws_size; (void)n_in; (void)in_sizes; (void)out_size;

  hipMemsetAsync(d_ws, 0, zbytes, stream);

  k_pro1<<<2850, 256, 0, stream>>>(edst, cnt, emb0, emb1, emb2, emb5, W1, tabs, row0, batch, gstart,
                                   W2, W3, Wbt2, Wbt3);
  k_scanA<<<13, 1024, 0, stream>>>(cnt, partials);
  k_scanB<<<1, 64, 0, stream>>>(partials, off);
  k_scanC<<<13, 1024, 0, stream>>>(cnt, partials, off, cursor, dinv, csr, Abf);
  k_pro2<<<14844, 256, 0, stream>>>(esrc, edst, cursor, csr, x, (const float2*)tabs,
                                    (const float2*)row0, dinv, Abf);

  const int nagg = NN / AGG_NPB;            // 3125, exact
  const int ngemm = (NN + 127) / 128;       // 391
  float* st1 = stats;
  float* st2 = stats + NSC * 256;
  float* st3 = stats + 2 * NSC * 256;

  // layer 1
  k_agg<<<nagg, 256, 0, stream>>>(Abf, off, csr, dinv, b1, Bbf, st1);
  // layer 2
  k_gemm<<<ngemm, 256, 0, stream>>>(Bbf, Wbt2, st1, g1, be1, dinv, Abf);
  k_agg<<<nagg, 256, 0, stream>>>(Abf, off, csr, dinv, b2, Bbf, st2);
  // layer 3
  k_gemm<<<ngemm, 256, 0, stream>>>(Bbf, Wbt3, st2, g2, be2, dinv, Abf);
  k_agg<<<nagg, 256, 0, stream>>>(Abf, off, csr, dinv, b3, Bbf, st3);
  // pool + fc
  k_pool<<<NG, 256, 0, stream>>>(Bbf, st3, g3, be3, gstart, fcW, fcb, out);
}

// Round 15
// 323.043 us; speedup vs baseline: 1.5102x; 1.2827x over previous
//
#include <hip/hip_runtime.h>

#define NN 50000
#define NE 600000
#define NG 512
#define HD 128
#define EPSV 1e-5f
#define NSC 64                        // stats scatter copies
#define PLNU ((size_t)(NN + 1) * 32)  // plane stride in uints (128B rows + pad row)

typedef unsigned int uint;
typedef __attribute__((ext_vector_type(8))) short short8;
typedef __attribute__((ext_vector_type(4))) float f32x4;

__device__ inline void atomicAddF(float* p, float v) {
  __hip_atomic_fetch_add(p, v, __ATOMIC_RELAXED, __HIP_MEMORY_SCOPE_AGENT);
}

__device__ inline uint bf16rne(float f) {
  uint u = __float_as_uint(f);
  return (u + 0x7fffu + ((u >> 16) & 1u)) >> 16;
}
__device__ inline uint pack2bf(float a, float b) {
  return bf16rne(a) | (bf16rne(b) << 16);
}
__device__ inline float lo16f(uint u) { return __uint_as_float(u << 16); }
__device__ inline float hi16f(uint u) { return __uint_as_float(u & 0xffff0000u); }

// ---- prologue 1: count (0..2343) + tabs (2344..2814) + bsearch (2815..2817)
//      + W2->Wbt2 (2818..2833) + W3->Wbt3 (2834..2849)
__global__ __launch_bounds__(256) void k_pro1(const int* __restrict__ dst, int* __restrict__ cnt,
                                              const float* __restrict__ emb0, const float* __restrict__ emb1,
                                              const float* __restrict__ emb2, const float* __restrict__ emb5,
                                              const float* __restrict__ W1, float* __restrict__ tabs,
                                              float* __restrict__ row0, const int* __restrict__ batch,
                                              int* __restrict__ gstart,
                                              const float* __restrict__ W2, const float* __restrict__ W3,
                                              uint* __restrict__ Wbt2, uint* __restrict__ Wbt3) {
  const int bid = blockIdx.x, t = threadIdx.x;
  if (bid < 2344) {
    int e = bid * 256 + t;
    if (e < NE) atomicAdd(&cnt[dst[e]], 1);
    return;
  }
  if (bid < 2815) {
    if (t >= 128) return;
    int r = bid - 2344, f = t;
    if (r == 470) { row0[f] = W1[f]; return; }
    const float* e;
    int wbase;
    if (r < 96)      { e = emb0 + r * 32;         wbase = 1;  }
    else if (r < 192){ e = emb1 + (r - 96) * 32;  wbase = 33; }
    else if (r < 288){ e = emb2 + (r - 192) * 32; wbase = 65; }
    else             { e = emb5 + (r - 288) * 32; wbase = 97; }
    float acc = 0.f;
#pragma unroll 8
    for (int k = 0; k < 32; k++) acc += e[k] * W1[(wbase + k) * HD + f];
    tabs[r * HD + f] = acc;
    return;
  }
  if (bid < 2818) {
    int g = (bid - 2815) * 256 + t;
    if (g > NG) return;
    if (g == NG) { gstart[NG] = NN; return; }
    int lo = 0, hi = NN;
    while (lo < hi) {
      int mid = (lo + hi) >> 1;
      if (batch[mid] < g) lo = mid + 1;
      else hi = mid;
    }
    gstart[g] = lo;
    return;
  }
  {
    // W transpose+bf16: Wbt[f][k] = bf16(W[k][f]); 16 blocks per matrix
    const float* W = (bid < 2834) ? W2 : W3;
    uint* Wbt = (bid < 2834) ? Wbt2 : Wbt3;
    int b = (bid < 2834) ? (bid - 2818) : (bid - 2834);
    int f = b * 8 + (t >> 5);
    int kq = (t & 31) * 4;
    float w0 = W[(kq + 0) * HD + f];
    float w1 = W[(kq + 1) * HD + f];
    float w2 = W[(kq + 2) * HD + f];
    float w3 = W[(kq + 3) * HD + f];
    Wbt[f * 64 + (t & 31) * 2 + 0] = pack2bf(w0, w1);
    Wbt[f * 64 + (t & 31) * 2 + 1] = pack2bf(w2, w3);
  }
}

// ---- 2-phase scan over deg+1 (tile = 4096 elems/block, 13 blocks) ----
__global__ __launch_bounds__(1024) void k_scanA(const int* __restrict__ cnt, int* __restrict__ partials) {
  int t = threadIdx.x;
  int i0 = blockIdx.x * 4096 + 4 * t;
  int s = 0;
#pragma unroll
  for (int j = 0; j < 4; j++) {
    int idx = i0 + j;
    s += (idx < NN) ? (cnt[idx] + 1) : 0;
  }
#pragma unroll
  for (int d = 1; d < 64; d <<= 1) s += __shfl_xor(s, d);
  __shared__ int wsum[16];
  if ((t & 63) == 0) wsum[t >> 6] = s;
  __syncthreads();
  if (t == 0) {
    int tot = 0;
#pragma unroll
    for (int i = 0; i < 16; i++) tot += wsum[i];
    partials[blockIdx.x] = tot;
  }
}

// scanC absorbs scanB: each block redundantly prefixes the 13 partials.
__global__ __launch_bounds__(1024) void k_scanC(const int* __restrict__ cnt, const int* __restrict__ partials,
                                                int* __restrict__ off, int* __restrict__ cursor,
                                                float* __restrict__ dinv, int* __restrict__ csr,
                                                uint* __restrict__ Abf) {
  __shared__ int part[16];
  __shared__ int partscan[16];
  __shared__ int baseoff[2];   // [0]=prefix before this block, [1]=grand total
  int t = threadIdx.x;
  int lane = t & 63, w = t >> 6;
  if (blockIdx.x == 0 && t < 64) {
    // zero pad row NN in both planes (32 uints each)
    Abf[(size_t)(t >> 5) * PLNU + (size_t)NN * 32 + (t & 31)] = 0u;
  }
  if (t == 0) {
    int pre = 0, tot = 0;
#pragma unroll
    for (int i = 0; i < 13; i++) {
      int v = partials[i];
      if (i < blockIdx.x) pre += v;
      tot += v;
    }
    baseoff[0] = pre;
    baseoff[1] = tot;
    if (blockIdx.x == 0) off[NN] = tot;
  }
  int i0 = blockIdx.x * 4096 + 4 * t;
  int c[4], v[4];
#pragma unroll
  for (int j = 0; j < 4; j++) {
    int idx = i0 + j;
    c[j] = (idx < NN) ? cnt[idx] : 0;
    v[j] = (idx < NN) ? (c[j] + 1) : 0;
  }
  int tsum = (v[0] + v[1]) + (v[2] + v[3]);
  int val = tsum;
#pragma unroll
  for (int s = 1; s < 64; s <<= 1) {
    int u = __shfl_up(val, s);
    if (lane >= s) val += u;
  }
  if (lane == 63) part[w] = val;
  __syncthreads();
  if (t == 0) {
    int acc = 0;
#pragma unroll
    for (int i = 0; i < 16; i++) { acc += part[i]; partscan[i] = acc; }
  }
  __syncthreads();
  int waveoff = (w > 0) ? partscan[w - 1] : 0;
  int run = val - tsum + waveoff + baseoff[0];
#pragma unroll
  for (int j = 0; j < 4; j++) {
    int idx = i0 + j;
    if (idx < NN) {
      off[idx] = run;
      cursor[idx] = run + 1;
      csr[run] = idx;                        // self-edge
      dinv[idx] = rsqrtf((float)c[j] + 1.0f);
      run += v[j];
    }
  }
}

// ---- prologue 2: fill (blocks 0..2343) + embed (2344..14843, plane writes) ----
__global__ __launch_bounds__(256) void k_pro2(const int* __restrict__ src, const int* __restrict__ dst,
                                              int* __restrict__ cursor, int* __restrict__ csr,
                                              const float* __restrict__ x, const float2* __restrict__ tabs2,
                                              const float2* __restrict__ row02, const float* __restrict__ dinv,
                                              uint* __restrict__ Abf) {
  const int bid = blockIdx.x, t = threadIdx.x;
  if (bid < 2344) {
    int e = bid * 256 + t;
    if (e < NE) {
      int p = atomicAdd(&cursor[dst[e]], 1);
      csr[p] = src[e];
    }
    return;
  }
  int n = (bid - 2344) * 4 + (t >> 6);   // exact: 12500*4 = NN
  int lane = t & 63;
  float poss = x[n * 5 + 0];
  int i0 = (int)x[n * 5 + 1];
  int i1 = (int)x[n * 5 + 2];
  int i2 = (int)x[n * 5 + 3];
  int i5 = (int)x[n * 5 + 4];
  float2 r0 = row02[lane];
  float2 t0 = tabs2[(size_t)i0 * 64 + lane];
  float2 t1 = tabs2[(size_t)(96 + i1) * 64 + lane];
  float2 t2 = tabs2[(size_t)(192 + i2) * 64 + lane];
  float2 t5 = tabs2[(size_t)(288 + i5) * 64 + lane];
  float hx = poss * r0.x + t0.x + t1.x + t2.x + t5.x;
  float hy = poss * r0.y + t0.y + t1.y + t2.y + t5.y;
  float dv = dinv[n];
  // features (2*lane, 2*lane+1) -> plane lane>>5, uint lane&31
  Abf[(size_t)(lane >> 5) * PLNU + (size_t)n * 32 + (lane & 31)] = pack2bf(hx * dv, hy * dv);
}

// ---- aggregation, plane version: 128B rows (one cache line), 8 rows/instr.
// Launched once per plane; each launch streams a 6.4MB working set.
// CSR = [self, neighbors...]; B[n][plane-half] = dinv[n]*sum(rows) + bias.
#define AGG_NPW 4
#define AGG_NPB (4 * AGG_NPW)
__global__ __launch_bounds__(256) void k_aggP(const uint* __restrict__ Ap, const int* __restrict__ off,
                                              const int* __restrict__ csr, const float* __restrict__ dinv,
                                              const float* __restrict__ bias, uint* __restrict__ Bbf,
                                              float* __restrict__ stats, const int plane) {
  const int t = threadIdx.x, lane = t & 63, wave = t >> 6;
  const int rg = lane >> 3, pl = lane & 7;
  __shared__ float sred[256];
  sred[t] = 0.f;
  __syncthreads();

  // lane pl owns features plane*64 + pl*8 .. +7
  const float4 ba = ((const float4*)bias)[plane * 16 + pl * 2];
  const float4 bb = ((const float4*)bias)[plane * 16 + pl * 2 + 1];

  const int n0 = blockIdx.x * AGG_NPB + wave * AGG_NPW;   // grid exact
  int sv = 0; float dvv = 0.f;
  {
    int q = n0 + lane;
    if (lane <= AGG_NPW) sv = off[q];
    if (lane < AGG_NPW) dvv = dinv[q];
  }

  // preload all 4 nodes' first-64 edge indices
  int ev[AGG_NPW];
#pragma unroll
  for (int i = 0; i < AGG_NPW; i++) {
    int ks = __shfl(sv, i), ke = __shfl(sv, i + 1);
    int rem = ke - ks;
    ev[i] = (lane < rem) ? csr[ks + lane] : NN;
  }

  // Phase 1: upfront clause — 4 nodes x 2 instr (16 neighbors each, pads->row NN)
  uint4 v[AGG_NPW][2];
#pragma unroll
  for (int i = 0; i < AGG_NPW; i++) {
#pragma unroll
    for (int m = 0; m < 2; m++) {
      int nb = __shfl(ev[i], m * 8 + rg);
      v[i][m] = *(const uint4*)(Ap + (size_t)nb * 32 + pl * 4);
    }
  }

  float st1[8] = {0.f,0.f,0.f,0.f,0.f,0.f,0.f,0.f};
  float st2[8] = {0.f,0.f,0.f,0.f,0.f,0.f,0.f,0.f};

  // Phase 2: per-node consume (fully unrolled)
#pragma unroll
  for (int i = 0; i < AGG_NPW; i++) {
    const int ks = __shfl(sv, i);
    const int ke = __shfl(sv, i + 1);
    const int deg = ke - ks;
    float acc[8];
#pragma unroll
    for (int j = 0; j < 8; j++) acc[j] = 0.f;
#pragma unroll
    for (int m = 0; m < 2; m++) {
      uint4 vv = v[i][m];
      acc[0] += lo16f(vv.x); acc[1] += hi16f(vv.x);
      acc[2] += lo16f(vv.y); acc[3] += hi16f(vv.y);
      acc[4] += lo16f(vv.z); acc[5] += hi16f(vv.z);
      acc[6] += lo16f(vv.w); acc[7] += hi16f(vv.w);
    }
    // tail: neighbors 16..deg, 8 per instruction
#pragma unroll 1
    for (int c0 = 16; c0 < deg; c0 += 8) {
      int nb;
      if (c0 + 8 <= 64) {
        nb = __shfl(ev[i], c0 + rg);           // pads give NN
      } else {
        int rem2 = deg - c0;
        int evr = (lane < rem2) ? csr[ks + c0 + lane] : NN;
        nb = __shfl(evr, rg);
      }
      uint4 w = *(const uint4*)(Ap + (size_t)nb * 32 + pl * 4);
      acc[0] += lo16f(w.x); acc[1] += hi16f(w.x);
      acc[2] += lo16f(w.y); acc[3] += hi16f(w.y);
      acc[4] += lo16f(w.z); acc[5] += hi16f(w.z);
      acc[6] += lo16f(w.w); acc[7] += hi16f(w.w);
    }
    // combine 8 row-groups (disjoint neighbor subsets)
#pragma unroll
    for (int j = 0; j < 8; j++) {
      acc[j] += __shfl_xor(acc[j], 8);
      acc[j] += __shfl_xor(acc[j], 16);
      acc[j] += __shfl_xor(acc[j], 32);
    }
    const float dv = __shfl(dvv, i);
    float o[8];
    o[0] = fmaf(acc[0], dv, ba.x); o[1] = fmaf(acc[1], dv, ba.y);
    o[2] = fmaf(acc[2], dv, ba.z); o[3] = fmaf(acc[3], dv, ba.w);
    o[4] = fmaf(acc[4], dv, bb.x); o[5] = fmaf(acc[5], dv, bb.y);
    o[6] = fmaf(acc[6], dv, bb.z); o[7] = fmaf(acc[7], dv, bb.w);
    if (rg == 0) {   // lanes 0-7: write node's plane-half + single-replica stats
      uint4 ob;
      ob.x = pack2bf(o[0], o[1]);
      ob.y = pack2bf(o[2], o[3]);
      ob.z = pack2bf(o[4], o[5]);
      ob.w = pack2bf(o[6], o[7]);
      *(uint4*)&Bbf[(size_t)(n0 + i) * 64 + plane * 32 + pl * 4] = ob;
#pragma unroll
      for (int j = 0; j < 8; j++) { st1[j] += o[j]; st2[j] += o[j] * o[j]; }
    }
  }
  if (lane < 8) {
    int fb = plane * 64 + pl * 8;
#pragma unroll
    for (int j = 0; j < 8; j++) {
      atomicAdd(&sred[fb + j], st1[j]);
      atomicAdd(&sred[128 + fb + j], st2[j]);
    }
  }
  __syncthreads();
  if (((t & 127) >> 6) == plane) {
    float* sp = stats + ((blockIdx.x & (NSC - 1)) << 8);   // 64-way scatter
    atomicAddF(&sp[t], sred[t]);
  }
}

// ---- GEMM via MFMA bf16: Abf-planes = bf16(dinv * (relu(affine(Bbf)) @ W)) ----
__global__ __launch_bounds__(256) void k_gemm(const uint* __restrict__ Bbf, const uint* __restrict__ Wbt,
                                              const float* __restrict__ stats, const float* __restrict__ gg,
                                              const float* __restrict__ be, const float* __restrict__ dinv,
                                              uint* __restrict__ Abf) {
  __shared__ uint hs[128 * 33];
  __shared__ uint ws[128 * 33];
  __shared__ float afl[128], cfl[128], dvl[128];
  const int t = threadIdx.x;
  const int base = blockIdx.x * 128;
  if (t < 128) {
    float s1 = 0.f, s2 = 0.f;
#pragma unroll 4
    for (int i = 0; i < NSC; i++) {
      s1 += stats[i * 256 + t];
      s2 += stats[i * 256 + 128 + t];
    }
    float mean = s1 * (1.f / NN);
    float var = fmaxf(s2 * (1.f / NN) - mean * mean, 0.f);
    float inv = rsqrtf(var + EPSV);
    float a = gg[t] * inv;
    afl[t] = a;
    cfl[t] = be[t] - mean * a;
    int gn = base + t;
    dvl[t] = (gn < NN) ? dinv[gn] : 0.f;
  }

  const int lane = t & 63, wave = t >> 6;
  const int r16 = lane & 15, hi = lane >> 4;
  const int nb = (wave & 1) * 64, fb = (wave >> 1) * 64;

  f32x4 acc00 = {0.f,0.f,0.f,0.f}, acc01 = acc00, acc02 = acc00, acc03 = acc00;
  f32x4 acc10 = acc00, acc11 = acc00, acc12 = acc00, acc13 = acc00;
  f32x4 acc20 = acc00, acc21 = acc00, acc22 = acc00, acc23 = acc00;
  f32x4 acc30 = acc00, acc31 = acc00, acc32 = acc00, acc33 = acc00;

#pragma unroll
  for (int kc = 0; kc < 2; kc++) {
    __syncthreads();
#pragma unroll
    for (int it = 0; it < 4; it++) {
      int idx = t + it * 256;            // 0..1023
      int n = idx >> 3, c4 = idx & 7;
      int gn = base + n;
      uint4 vv = make_uint4(0u, 0u, 0u, 0u);
      if (gn < NN) vv = *(const uint4*)&Bbf[(size_t)gn * 64 + kc * 32 + c4 * 4];
      int k0 = kc * 64 + c4 * 8;
      uint r0 = pack2bf(fmaxf(fmaf(afl[k0+0], lo16f(vv.x), cfl[k0+0]), 0.f),
                        fmaxf(fmaf(afl[k0+1], hi16f(vv.x), cfl[k0+1]), 0.f));
      uint r1 = pack2bf(fmaxf(fmaf(afl[k0+2], lo16f(vv.y), cfl[k0+2]), 0.f),
                        fmaxf(fmaf(afl[k0+3], hi16f(vv.y), cfl[k0+3]), 0.f));
      uint r2 = pack2bf(fmaxf(fmaf(afl[k0+4], lo16f(vv.z), cfl[k0+4]), 0.f),
                        fmaxf(fmaf(afl[k0+5], hi16f(vv.z), cfl[k0+5]), 0.f));
      uint r3 = pack2bf(fmaxf(fmaf(afl[k0+6], lo16f(vv.w), cfl[k0+6]), 0.f),
                        fmaxf(fmaf(afl[k0+7], hi16f(vv.w), cfl[k0+7]), 0.f));
      hs[n * 33 + c4 * 4 + 0] = r0;
      hs[n * 33 + c4 * 4 + 1] = r1;
      hs[n * 33 + c4 * 4 + 2] = r2;
      hs[n * 33 + c4 * 4 + 3] = r3;
    }
#pragma unroll
    for (int it = 0; it < 4; it++) {
      int idx = t + it * 256;
      int f = idx >> 3, c4 = idx & 7;
      uint4 vv = *(const uint4*)&Wbt[(size_t)f * 64 + kc * 32 + c4 * 4];
      *(uint4*)&ws[f * 33 + c4 * 4] = vv;
    }
    __syncthreads();
#pragma unroll
    for (int ksl = 0; ksl < 2; ksl++) {
      int ko = ksl * 16 + hi * 4;
      short8 a0 = *(short8*)&hs[(nb + 0 * 16 + r16) * 33 + ko];
      short8 a1 = *(short8*)&hs[(nb + 1 * 16 + r16) * 33 + ko];
      short8 a2 = *(short8*)&hs[(nb + 2 * 16 + r16) * 33 + ko];
      short8 a3 = *(short8*)&hs[(nb + 3 * 16 + r16) * 33 + ko];
      short8 b0 = *(short8*)&ws[(fb + 0 * 16 + r16) * 33 + ko];
      short8 b1 = *(short8*)&ws[(fb + 1 * 16 + r16) * 33 + ko];
      short8 b2 = *(short8*)&ws[(fb + 2 * 16 + r16) * 33 + ko];
      short8 b3 = *(short8*)&ws[(fb + 3 * 16 + r16) * 33 + ko];
      acc00 = __builtin_amdgcn_mfma_f32_16x16x32_bf16(a0, b0, acc00, 0, 0, 0);
      acc01 = __builtin_amdgcn_mfma_f32_16x16x32_bf16(a0, b1, acc01, 0, 0, 0);
      acc02 = __builtin_amdgcn_mfma_f32_16x16x32_bf16(a0, b2, acc02, 0, 0, 0);
      acc03 = __builtin_amdgcn_mfma_f32_16x16x32_bf16(a0, b3, acc03, 0, 0, 0);
      acc10 = __builtin_amdgcn_mfma_f32_16x16x32_bf16(a1, b0, acc10, 0, 0, 0);
      acc11 = __builtin_amdgcn_mfma_f32_16x16x32_bf16(a1, b1, acc11, 0, 0, 0);
      acc12 = __builtin_amdgcn_mfma_f32_16x16x32_bf16(a1, b2, acc12, 0, 0, 0);
      acc13 = __builtin_amdgcn_mfma_f32_16x16x32_bf16(a1, b3, acc13, 0, 0, 0);
      acc20 = __builtin_amdgcn_mfma_f32_16x16x32_bf16(a2, b0, acc20, 0, 0, 0);
      acc21 = __builtin_amdgcn_mfma_f32_16x16x32_bf16(a2, b1, acc21, 0, 0, 0);
      acc22 = __builtin_amdgcn_mfma_f32_16x16x32_bf16(a2, b2, acc22, 0, 0, 0);
      acc23 = __builtin_amdgcn_mfma_f32_16x16x32_bf16(a2, b3, acc23, 0, 0, 0);
      acc30 = __builtin_amdgcn_mfma_f32_16x16x32_bf16(a3, b0, acc30, 0, 0, 0);
      acc31 = __builtin_amdgcn_mfma_f32_16x16x32_bf16(a3, b1, acc31, 0, 0, 0);
      acc32 = __builtin_amdgcn_mfma_f32_16x16x32_bf16(a3, b2, acc32, 0, 0, 0);
      acc33 = __builtin_amdgcn_mfma_f32_16x16x32_bf16(a3, b3, acc33, 0, 0, 0);
    }
  }

  // epilogue -> plane layout; C map: col=lane&15 (f), row=(lane>>4)*4+reg [m89]
  unsigned short* A16 = (unsigned short*)Abf;
  const size_t PLNH = (size_t)(NN + 1) * 64;   // halfwords per plane
#define STORE_TILE(ACC, M, N) { \
    _Pragma("unroll") \
    for (int reg = 0; reg < 4; reg++) { \
      int nl = nb + (M) * 16 + hi * 4 + reg; \
      int gn = base + nl; \
      if (gn < NN) { \
        float val = ACC[reg] * dvl[nl]; \
        int f = fb + (N) * 16 + r16; \
        A16[(size_t)(f >> 6) * PLNH + (size_t)gn * 64 + (f & 63)] = (unsigned short)bf16rne(val); \
      } \
    } }
  STORE_TILE(acc00, 0, 0) STORE_TILE(acc01, 0, 1) STORE_TILE(acc02, 0, 2) STORE_TILE(acc03, 0, 3)
  STORE_TILE(acc10, 1, 0) STORE_TILE(acc11, 1, 1) STORE_TILE(acc12, 1, 2) STORE_TILE(acc13, 1, 3)
  STORE_TILE(acc20, 2, 0) STORE_TILE(acc21, 2, 1) STORE_TILE(acc22, 2, 2) STORE_TILE(acc23, 2, 3)
  STORE_TILE(acc30, 3, 0) STORE_TILE(acc31, 3, 1) STORE_TILE(acc32, 3, 2) STORE_TILE(acc33, 3, 3)
#undef STORE_TILE
}

// ---- pool + FC (affine folded in; bf16 input; 2 node-lanes x 128 features) ----
__global__ __launch_bounds__(256) void k_pool(const uint* __restrict__ Bbf, const float* __restrict__ stats,
                                              const float* __restrict__ gg, const float* __restrict__ be,
                                              const int* __restrict__ gstart,
                                              const float* __restrict__ fcW, const float* __restrict__ fcb,
                                              float* __restrict__ out) {
  __shared__ float afl[128], cfl[128];
  int t = threadIdx.x;
  if (t < 128) {
    float s1 = 0.f, s2 = 0.f;
#pragma unroll 4
    for (int i = 0; i < NSC; i++) {
      s1 += stats[i * 256 + t];
      s2 += stats[i * 256 + 128 + t];
    }
    float mean = s1 * (1.f / NN);
    float var = fmaxf(s2 * (1.f / NN) - mean * mean, 0.f);
    float inv = rsqrtf(var + EPSV);
    float a = gg[t] * inv;
    afl[t] = a;
    cfl[t] = be[t] - mean * a;
  }
  __syncthreads();

  int g = blockIdx.x;
  int r = t >> 7, f = t & 127;
  int gs = gstart[g], ge = gstart[g + 1];
  float a = afl[f], c = cfl[f];
  int half = f >> 1;   // uint index within 64-uint row
  int odd = f & 1;
  float a0 = 0.f, a1 = 0.f, a2 = 0.f, a3 = 0.f;
  int n = gs + r;
  for (; n + 6 < ge; n += 8) {
    uint u0 = Bbf[(size_t)(n + 0) * 64 + half];
    uint u1 = Bbf[(size_t)(n + 2) * 64 + half];
    uint u2 = Bbf[(size_t)(n + 4) * 64 + half];
    uint u3 = Bbf[(size_t)(n + 6) * 64 + half];
    a0 += fmaxf(fmaf(a, odd ? hi16f(u0) : lo16f(u0), c), 0.f);
    a1 += fmaxf(fmaf(a, odd ? hi16f(u1) : lo16f(u1), c), 0.f);
    a2 += fmaxf(fmaf(a, odd ? hi16f(u2) : lo16f(u2), c), 0.f);
    a3 += fmaxf(fmaf(a, odd ? hi16f(u3) : lo16f(u3), c), 0.f);
  }
  for (; n < ge; n += 2) {
    uint u0 = Bbf[(size_t)n * 64 + half];
    a0 += fmaxf(fmaf(a, odd ? hi16f(u0) : lo16f(u0), c), 0.f);
  }
  float acc = (a0 + a1) + (a2 + a3);
  __shared__ float lp[256];
  lp[t] = acc;
  __syncthreads();
  if (r == 0) {
    float pooled = (lp[f] + lp[f + 128]) / fmaxf((float)(ge - gs), 1.f);
    lp[f] = pooled;
  }
  __syncthreads();
  if (t < 3) {
    float o = fcb[t];
    for (int k = 0; k < 128; k++) o += lp[k] * fcW[k * 3 + t];
    out[g * 3 + t] = o;
  }
}

extern "C" void kernel_launch(void* const* d_in, const int* in_sizes, int n_in,
                              void* d_out, int out_size, void* d_ws, size_t ws_size,
                              hipStream_t stream) {
  const float* x    = (const float*)d_in[0];
  const int* ei     = (const int*)d_in[1];
  const int* batch  = (const int*)d_in[2];
  const float* emb0 = (const float*)d_in[3];
  const float* emb1 = (const float*)d_in[4];
  const float* emb2 = (const float*)d_in[5];
  const float* emb5 = (const float*)d_in[6];
  const float* W1   = (const float*)d_in[7];
  const float* b1   = (const float*)d_in[8];
  const float* W2   = (const float*)d_in[9];
  const float* b2   = (const float*)d_in[10];
  const float* W3   = (const float*)d_in[11];
  const float* b3   = (const float*)d_in[12];
  const float* g1   = (const float*)d_in[13];
  const float* be1  = (const float*)d_in[14];
  const float* g2   = (const float*)d_in[15];
  const float* be2  = (const float*)d_in[16];
  const float* g3   = (const float*)d_in[17];
  const float* be3  = (const float*)d_in[18];
  const float* fcW  = (const float*)d_in[19];
  const float* fcb  = (const float*)d_in[20];
  float* out = (float*)d_out;

  const int* esrc = ei;
  const int* edst = ei + NE;

  char* p = (char*)d_ws;
  size_t o = 0;
  auto alloc = [&](size_t bytes) -> void* {
    o = (o + 255) & ~(size_t)255;
    void* r = p + o;
    o += bytes;
    return r;
  };
  int* cnt      = (int*)alloc(NN * 4);
  float* stats  = (float*)alloc(3 * NSC * 256 * 4);   // 3 layers x 64 copies x (sum,sumsq)
  size_t zbytes = o;                                  // memset covers cnt+stats
  int* off      = (int*)alloc((NN + 1) * 4);
  int* cursor   = (int*)alloc(NN * 4);
  int* csr      = (int*)alloc((size_t)(NE + NN + 64) * 4);
  float* dinv   = (float*)alloc(NN * 4);
  float* tabs   = (float*)alloc(470 * HD * 4);
  float* row0   = (float*)alloc(HD * 4);
  int* gstart   = (int*)alloc((NG + 1) * 4);
  int* partials = (int*)alloc(16 * 4);
  uint* Abf     = (uint*)alloc((size_t)2 * PLNU * 4);   // 2 planes of 128B rows (+pad row each)
  uint* Bbf     = (uint*)alloc((size_t)NN * 64 * 4);    // bf16 agg output (256B rows)
  uint* Wbt2    = (uint*)alloc(128 * 64 * 4);
  uint* Wbt3    = (uint*)alloc(128 * 64 * 4);
  (void)ws_size; (void)n_in; (void)in_sizes; (void)out_size;

  hipMemsetAsync(d_ws, 0, zbytes, stream);

  k_pro1<<<2850, 256, 0, stream>>>(edst, cnt, emb0, emb1, emb2, emb5, W1, tabs, row0, batch, gstart,
                                   W2, W3, Wbt2, Wbt3);
  k_scanA<<<13, 1024, 0, stream>>>(cnt, partials);
  k_scanC<<<13, 1024, 0, stream>>>(cnt, partials, off, cursor, dinv, csr, Abf);
  k_pro2<<<14844, 256, 0, stream>>>(esrc, edst, cursor, csr, x, (const float2*)tabs,
                                    (const float2*)row0, dinv, Abf);

  const int nagg = NN / AGG_NPB;            // 3125, exact
  const int ngemm = (NN + 127) / 128;       // 391
  float* st1 = stats;
  float* st2 = stats + NSC * 256;
  float* st3 = stats + 2 * NSC * 256;
  uint* Ap0 = Abf;
  uint* Ap1 = Abf + PLNU;

  // layer 1
  k_aggP<<<nagg, 256, 0, stream>>>(Ap0, off, csr, dinv, b1, Bbf, st1, 0);
  k_aggP<<<nagg, 256, 0, stream>>>(Ap1, off, csr, dinv, b1, Bbf, st1, 1);
  // layer 2
  k_gemm<<<ngemm, 256, 0, stream>>>(Bbf, Wbt2, st1, g1, be1, dinv, Abf);
  k_aggP<<<nagg, 256, 0, stream>>>(Ap0, off, csr, dinv, b2, Bbf, st2, 0);
  k_aggP<<<nagg, 256, 0, stream>>>(Ap1, off, csr, dinv, b2, Bbf, st2, 1);
  // layer 3
  k_gemm<<<ngemm, 256, 0, stream>>>(Bbf, Wbt3, st2, g2, be2, dinv, Abf);
  k_aggP<<<nagg, 256, 0, stream>>>(Ap0, off, csr, dinv, b3, Bbf, st3, 0);
  k_aggP<<<nagg, 256, 0, stream>>>(Ap1, off, csr, dinv, b3, Bbf, st3, 1);
  // pool + fc
  k_pool<<<NG, 256, 0, stream>>>(Bbf, st3, g3, be3, gstart, fcW, fcb, out);
}